// Round 1
// baseline (446.335 us; speedup 1.0000x reference)
//
#include <hip/hip_runtime.h>
#include <hip/hip_bf16.h>

#define A_TOK 2048
#define DDIM 1024
#define FDIM 2048
#define NEXP 8

#define BM 128
#define BN 128
#define BK 32

typedef __attribute__((ext_vector_type(8))) short short8v;  // 8 bf16 (4 VGPR)
typedef __attribute__((ext_vector_type(4))) float f32x4;

__device__ __forceinline__ void lds16(const void* g, void* l) {
  __builtin_amdgcn_global_load_lds((const __attribute__((address_space(1))) void*)g,
                                   (__attribute__((address_space(3))) void*)l, 16, 0, 0);
}

__device__ __forceinline__ float sigmoidf_(float x) { return 1.f / (1.f + __expf(-x)); }

// ---------------- weight prep ----------------
__global__ void k_cvt(const float* __restrict__ in, __hip_bfloat16* __restrict__ out, int n) {
  int i = blockIdx.x * blockDim.x + threadIdx.x;
  int stride = gridDim.x * blockDim.x;
  for (int j = i * 4; j < n; j += stride * 4) {
    float4 v = *(const float4*)(in + j);
    out[j + 0] = __float2bfloat16(v.x);
    out[j + 1] = __float2bfloat16(v.y);
    out[j + 2] = __float2bfloat16(v.z);
    out[j + 3] = __float2bfloat16(v.w);
  }
}

// in: fp32 [R][C] (+z*R*C) -> out: bf16 [C][R] (+z*R*C)
__global__ void k_transpose(const float* __restrict__ in, __hip_bfloat16* __restrict__ out,
                            int R, int C) {
  __shared__ __hip_bfloat16 tile[64][66];  // row stride 132 B -> conflict-free transpose read
  size_t zofs = (size_t)blockIdx.z * R * C;
  in += zofs; out += zofs;
  int r0 = blockIdx.y * 64, c0 = blockIdx.x * 64;
  int rr = threadIdx.x >> 6;   // 0..3
  int cc = threadIdx.x & 63;
#pragma unroll
  for (int i = 0; i < 16; i++) {
    int r = i * 4 + rr;
    tile[r][cc] = __float2bfloat16(in[(size_t)(r0 + r) * C + c0 + cc]);
  }
  __syncthreads();
#pragma unroll
  for (int i = 0; i < 16; i++) {
    int c = i * 4 + rr;
    out[(size_t)(c0 + c) * R + r0 + cc] = tile[cc][c];
  }
}

// ---------------- router ----------------
__global__ void k_router(const float* __restrict__ x, const float* __restrict__ rw,
                         __hip_bfloat16* __restrict__ xbf, int* __restrict__ counts,
                         int* __restrict__ top_e, float* __restrict__ top_g) {
  int t = blockIdx.x * 4 + (threadIdx.x >> 6);
  int l = threadIdx.x & 63;
  const float* xr = x + (size_t)t * DDIM;
  float acc[NEXP];
#pragma unroll
  for (int e = 0; e < NEXP; e++) acc[e] = 0.f;
#pragma unroll
  for (int i = 0; i < 16; i++) {
    int d = i * 64 + l;
    float v = xr[d];
    xbf[(size_t)t * DDIM + d] = __float2bfloat16(v);
    const float* rr = rw + (size_t)d * NEXP;
#pragma unroll
    for (int e = 0; e < NEXP; e++) acc[e] += v * rr[e];
  }
#pragma unroll
  for (int e = 0; e < NEXP; e++) {
#pragma unroll
    for (int s = 32; s > 0; s >>= 1) acc[e] += __shfl_xor(acc[e], s);
  }
  if (l == 0) {
    float b1 = -1e30f, b2 = -1e30f;
    int i1 = 0, i2 = 0;
#pragma unroll
    for (int e = 0; e < NEXP; e++) {
      float v = acc[e];
      if (v > b1) { b2 = b1; i2 = i1; b1 = v; i1 = e; }
      else if (v > b2) { b2 = v; i2 = e; }
    }
    atomicAdd(&counts[i1], 1);
    atomicAdd(&counts[i2], 1);
    top_e[t * 2 + 0] = i1; top_e[t * 2 + 1] = i2;
    top_g[t * 2 + 0] = sigmoidf_(b1); top_g[t * 2 + 1] = sigmoidf_(b2);
  }
}

__global__ void k_scan(const int* __restrict__ counts, int* __restrict__ offs,
                       int* __restrict__ cursor) {
  if (threadIdx.x == 0 && blockIdx.x == 0) {
    int s = 0;
    for (int e = 0; e < NEXP; e++) { offs[e] = s; s += counts[e]; cursor[e] = 0; }
  }
}

__global__ void k_dispatch(const float* __restrict__ x, const int* __restrict__ top_e,
                           const float* __restrict__ top_g, const int* __restrict__ offs,
                           int* __restrict__ cursor, int* __restrict__ tok_of,
                           __hip_bfloat16* __restrict__ y) {
  int t = blockIdx.x * 4 + (threadIdx.x >> 6);
  int l = threadIdx.x & 63;
  int e0 = top_e[t * 2 + 0], e1 = top_e[t * 2 + 1];
  float g0 = top_g[t * 2 + 0], g1 = top_g[t * 2 + 1];
  int s0 = 0, s1 = 0;
  if (l == 0) {
    s0 = offs[e0] + atomicAdd(&cursor[e0], 1);
    s1 = offs[e1] + atomicAdd(&cursor[e1], 1);
    tok_of[s0] = t; tok_of[s1] = t;
  }
  s0 = __shfl(s0, 0); s1 = __shfl(s1, 0);
  const float* xr = x + (size_t)t * DDIM;
#pragma unroll
  for (int i = 0; i < 16; i++) {
    int d = i * 64 + l;
    float v = xr[d];
    y[(size_t)s0 * DDIM + d] = __float2bfloat16(v * g0);
    y[(size_t)s1 * DDIM + d] = __float2bfloat16(v * g1);
  }
}

// ---------------- fused in+swiglu GEMM: h = silu(A@B1^T) * (A@B2^T), bf16 out ----------------
// A: bf16 [rows][K] (row roff+m0+..), B1/B2: bf16 [N][K] (+e*b_stride), O: bf16 [rows][N]
__global__ __launch_bounds__(256, 2) void k_in_swiglu(
    const ushort* __restrict__ Abase, const ushort* __restrict__ B1base,
    const ushort* __restrict__ B2base, ushort* __restrict__ Obase,
    const int* __restrict__ d_cnt, const int* __restrict__ d_off,
    int K, int N, size_t b_stride) {
  int e = blockIdx.z;
  int cnt = d_cnt ? d_cnt[e] : A_TOK;
  int m0 = blockIdx.y * BM;
  if (m0 >= cnt) return;
  int roff = d_off ? d_off[e] : 0;
  int n0 = blockIdx.x * BN;
  const char* B1 = (const char*)(B1base + (size_t)e * b_stride);
  const char* B2 = (const char*)(B2base + (size_t)e * b_stride);

  __shared__ __align__(16) ushort sA[BM * BK];
  __shared__ __align__(16) ushort sB1[BN * BK];
  __shared__ __align__(16) ushort sB2[BN * BK];

  int tid = threadIdx.x;
  int w = tid >> 6, l = tid & 63;
  int wm = w >> 1, wn = w & 1;
  int lr = l & 15, kg = l >> 4;

  f32x4 acc1[4][4], acc2[4][4];
#pragma unroll
  for (int i = 0; i < 4; i++)
#pragma unroll
    for (int j = 0; j < 4; j++) {
      acc1[i][j] = {0.f, 0.f, 0.f, 0.f};
      acc2[i][j] = {0.f, 0.f, 0.f, 0.f};
    }

  size_t arow0 = (size_t)roff + m0;
  for (int k0 = 0; k0 < K; k0 += BK) {
    __syncthreads();
#pragma unroll
    for (int t2 = 0; t2 < 2; t2++) {
      int ofs = (tid + t2 * 256) * 16;
      int row = ofs >> 6, inb = ofs & 63;
      lds16((const char*)Abase + (((arow0 + row) * (size_t)K + k0) << 1) + inb, (char*)sA + ofs);
      lds16(B1 + (((size_t)(n0 + row) * (size_t)K + k0) << 1) + inb, (char*)sB1 + ofs);
      lds16(B2 + (((size_t)(n0 + row) * (size_t)K + k0) << 1) + inb, (char*)sB2 + ofs);
    }
    __syncthreads();
    short8v af[4];
#pragma unroll
    for (int im = 0; im < 4; im++)
      af[im] = *(const short8v*)&sA[(wm * 64 + im * 16 + lr) * BK + kg * 8];
#pragma unroll
    for (int in = 0; in < 4; in++) {
      short8v b1f = *(const short8v*)&sB1[(wn * 64 + in * 16 + lr) * BK + kg * 8];
      short8v b2f = *(const short8v*)&sB2[(wn * 64 + in * 16 + lr) * BK + kg * 8];
#pragma unroll
      for (int im = 0; im < 4; im++) {
        acc1[im][in] = __builtin_amdgcn_mfma_f32_16x16x32_bf16(af[im], b1f, acc1[im][in], 0, 0, 0);
        acc2[im][in] = __builtin_amdgcn_mfma_f32_16x16x32_bf16(af[im], b2f, acc2[im][in], 0, 0, 0);
      }
    }
  }
#pragma unroll
  for (int im = 0; im < 4; im++)
#pragma unroll
    for (int in = 0; in < 4; in++)
#pragma unroll
      for (int r = 0; r < 4; r++) {
        int row = m0 + wm * 64 + im * 16 + kg * 4 + r;
        if (row < cnt) {
          float mid = acc1[im][in][r];
          float sw = acc2[im][in][r];
          float h = mid * sigmoidf_(mid) * sw;
          int col = n0 + wn * 64 + in * 16 + lr;
          __hip_bfloat16 hb = __float2bfloat16(h);
          ushort u; __builtin_memcpy(&u, &hb, 2);
          Obase[((size_t)roff + row) * N + col] = u;
        }
      }
}

// ---------------- out-proj GEMM: C = A@B^T, fp32 out (store or atomic via token map) ----------
__global__ __launch_bounds__(256, 2) void k_out(
    const ushort* __restrict__ Abase, const ushort* __restrict__ Bbase,
    float* __restrict__ out, const int* __restrict__ d_cnt, const int* __restrict__ d_off,
    const int* __restrict__ tok_of, int K, size_t b_stride, int routed) {
  int e = blockIdx.z;
  int cnt = routed ? d_cnt[e] : A_TOK;
  int m0 = blockIdx.y * BM;
  if (m0 >= cnt) return;
  int roff = routed ? d_off[e] : 0;
  int n0 = blockIdx.x * BN;
  const char* B = (const char*)(Bbase + (size_t)e * b_stride);

  __shared__ __align__(16) ushort sA[BM * BK];
  __shared__ __align__(16) ushort sB[BN * BK];

  int tid = threadIdx.x;
  int w = tid >> 6, l = tid & 63;
  int wm = w >> 1, wn = w & 1;
  int lr = l & 15, kg = l >> 4;

  f32x4 acc[4][4];
#pragma unroll
  for (int i = 0; i < 4; i++)
#pragma unroll
    for (int j = 0; j < 4; j++) acc[i][j] = {0.f, 0.f, 0.f, 0.f};

  size_t arow0 = (size_t)roff + m0;
  for (int k0 = 0; k0 < K; k0 += BK) {
    __syncthreads();
#pragma unroll
    for (int t2 = 0; t2 < 2; t2++) {
      int ofs = (tid + t2 * 256) * 16;
      int row = ofs >> 6, inb = ofs & 63;
      lds16((const char*)Abase + (((arow0 + row) * (size_t)K + k0) << 1) + inb, (char*)sA + ofs);
      lds16(B + (((size_t)(n0 + row) * (size_t)K + k0) << 1) + inb, (char*)sB + ofs);
    }
    __syncthreads();
    short8v af[4];
#pragma unroll
    for (int im = 0; im < 4; im++)
      af[im] = *(const short8v*)&sA[(wm * 64 + im * 16 + lr) * BK + kg * 8];
#pragma unroll
    for (int in = 0; in < 4; in++) {
      short8v bf = *(const short8v*)&sB[(wn * 64 + in * 16 + lr) * BK + kg * 8];
#pragma unroll
      for (int im = 0; im < 4; im++)
        acc[im][in] = __builtin_amdgcn_mfma_f32_16x16x32_bf16(af[im], bf, acc[im][in], 0, 0, 0);
    }
  }
#pragma unroll
  for (int im = 0; im < 4; im++)
#pragma unroll
    for (int in = 0; in < 4; in++)
#pragma unroll
      for (int r = 0; r < 4; r++) {
        int row = m0 + wm * 64 + im * 16 + kg * 4 + r;
        if (row < cnt) {
          int col = n0 + wn * 64 + in * 16 + lr;
          float v = acc[im][in][r];
          if (routed) {
            int t = tok_of[roff + row];
            atomicAdd(&out[(size_t)t * DDIM + col], v);
          } else {
            out[(size_t)row * DDIM + col] = v;
          }
        }
      }
}

extern "C" void kernel_launch(void* const* d_in, const int* in_sizes, int n_in,
                              void* d_out, int out_size, void* d_ws, size_t ws_size,
                              hipStream_t stream) {
  (void)in_sizes; (void)n_in; (void)out_size; (void)ws_size;
  const float* x        = (const float*)d_in[0];
  const float* router   = (const float*)d_in[1];
  const float* w_in_sh  = (const float*)d_in[2];
  const float* w_out_sh = (const float*)d_in[3];
  const float* w_sw_sh  = (const float*)d_in[4];
  const float* w_in_e   = (const float*)d_in[5];
  const float* w_sw_e   = (const float*)d_in[6];
  const float* w_out_e  = (const float*)d_in[7];
  float* out = (float*)d_out;

  char* ws = (char*)d_ws;
  size_t off = 0;
  auto alloc = [&](size_t bytes) -> char* {
    char* p = ws + off;
    off += (bytes + 255) & ~(size_t)255;
    return p;
  };
  // NOTE: ordering matters — partial-tile A overreads from y_all spill into h_r,
  // and from h_r into h_sh (both harmless; stores are count-guarded).
  __hip_bfloat16* wt_in_t  = (__hip_bfloat16*)alloc((size_t)NEXP * FDIM * DDIM * 2);
  __hip_bfloat16* wt_sw_t  = (__hip_bfloat16*)alloc((size_t)NEXP * FDIM * DDIM * 2);
  __hip_bfloat16* wt_out_t = (__hip_bfloat16*)alloc((size_t)NEXP * DDIM * FDIM * 2);
  __hip_bfloat16* wsh_in   = (__hip_bfloat16*)alloc((size_t)FDIM * DDIM * 2);
  __hip_bfloat16* wsh_sw   = (__hip_bfloat16*)alloc((size_t)FDIM * DDIM * 2);
  __hip_bfloat16* wsh_out  = (__hip_bfloat16*)alloc((size_t)DDIM * FDIM * 2);
  __hip_bfloat16* xbf      = (__hip_bfloat16*)alloc((size_t)A_TOK * DDIM * 2);
  __hip_bfloat16* y_all    = (__hip_bfloat16*)alloc((size_t)2 * A_TOK * DDIM * 2);
  __hip_bfloat16* h_r      = (__hip_bfloat16*)alloc((size_t)2 * A_TOK * FDIM * 2);
  __hip_bfloat16* h_sh     = (__hip_bfloat16*)alloc((size_t)A_TOK * FDIM * 2);
  int*   counts = (int*)alloc(64);
  int*   offs   = (int*)alloc(64);
  int*   cursor = (int*)alloc(64);
  int*   top_e  = (int*)alloc((size_t)A_TOK * 2 * 4);
  float* top_g  = (float*)alloc((size_t)A_TOK * 2 * 4);
  int*   tok_of = (int*)alloc((size_t)2 * A_TOK * 4);

  hipMemsetAsync(counts, 0, 64, stream);

  // weight prep: bf16 convert (shared, already K-contiguous) + transpose-convert (routed)
  k_cvt<<<dim3(2048), 256, 0, stream>>>(w_in_sh, wsh_in, FDIM * DDIM);
  k_cvt<<<dim3(2048), 256, 0, stream>>>(w_sw_sh, wsh_sw, FDIM * DDIM);
  k_cvt<<<dim3(2048), 256, 0, stream>>>(w_out_sh, wsh_out, DDIM * FDIM);
  k_transpose<<<dim3(FDIM / 64, DDIM / 64, NEXP), 256, 0, stream>>>(w_in_e, wt_in_t, DDIM, FDIM);
  k_transpose<<<dim3(FDIM / 64, DDIM / 64, NEXP), 256, 0, stream>>>(w_sw_e, wt_sw_t, DDIM, FDIM);
  k_transpose<<<dim3(DDIM / 64, FDIM / 64, NEXP), 256, 0, stream>>>(w_out_e, wt_out_t, FDIM, DDIM);

  // routing
  k_router<<<dim3(A_TOK / 4), 256, 0, stream>>>(x, router, xbf, counts, top_e, top_g);
  k_scan<<<1, 64, 0, stream>>>(counts, offs, cursor);
  k_dispatch<<<dim3(A_TOK / 4), 256, 0, stream>>>(x, top_e, top_g, offs, cursor, tok_of, y_all);

  // routed in+swiglu: per expert, M=cnt[e], N=F, K=D
  k_in_swiglu<<<dim3(FDIM / BN, A_TOK / BM, NEXP), 256, 0, stream>>>(
      (const ushort*)y_all, (const ushort*)wt_in_t, (const ushort*)wt_sw_t,
      (ushort*)h_r, counts, offs, DDIM, FDIM, (size_t)FDIM * DDIM);
  // shared in+swiglu: M=2048, N=F, K=D
  k_in_swiglu<<<dim3(FDIM / BN, A_TOK / BM, 1), 256, 0, stream>>>(
      (const ushort*)xbf, (const ushort*)wsh_in, (const ushort*)wsh_sw,
      (ushort*)h_sh, nullptr, nullptr, DDIM, FDIM, 0);

  // shared out-proj: overwrites every d_out element (handles poison), M=2048, N=D, K=F
  k_out<<<dim3(DDIM / BN, A_TOK / BM, 1), 256, 0, stream>>>(
      (const ushort*)h_sh, (const ushort*)wsh_out, out, nullptr, nullptr, nullptr,
      FDIM, 0, 0);
  // routed out-proj: atomicAdd into d_out via token map
  k_out<<<dim3(DDIM / BN, A_TOK / BM, NEXP), 256, 0, stream>>>(
      (const ushort*)h_r, (const ushort*)wt_out_t, out, counts, offs, tok_of,
      FDIM, (size_t)DDIM * FDIM, 1);
}

// Round 2
// 316.705 us; speedup vs baseline: 1.4093x; 1.4093x over previous
//
#include <hip/hip_runtime.h>
#include <hip/hip_bf16.h>

#define A_TOK 2048
#define DDIM 1024
#define FDIM 2048
#define NEXP 8
#define NE9 9                      // 8 routed + 1 shared pseudo-expert
#define SLOTS_R (2 * A_TOK)        // 4096 routed slots
#define SLOTS_T (SLOTS_R + A_TOK)  // 6144 incl. shared rows

#define BM 128
#define BN 128
#define BK 32

typedef __attribute__((ext_vector_type(8))) short short8v;  // 8 bf16 (4 VGPR)
typedef __attribute__((ext_vector_type(4))) float f32x4;

__device__ __forceinline__ void lds16(const void* g, void* l) {
  __builtin_amdgcn_global_load_lds((const __attribute__((address_space(1))) void*)g,
                                   (__attribute__((address_space(3))) void*)l, 16, 0, 0);
}

__device__ __forceinline__ float sigmoidf_(float x) { return 1.f / (1.f + __expf(-x)); }

// ---------------- weight prep ----------------
// z selects one of the 3 shared-weight fp32->bf16 conversions (into expert-slot 8).
__global__ void k_cvt3(const float* __restrict__ s0, const float* __restrict__ s1,
                       const float* __restrict__ s2, __hip_bfloat16* __restrict__ d0,
                       __hip_bfloat16* __restrict__ d1, __hip_bfloat16* __restrict__ d2) {
  const float* in = blockIdx.z == 0 ? s0 : (blockIdx.z == 1 ? s1 : s2);
  __hip_bfloat16* out = blockIdx.z == 0 ? d0 : (blockIdx.z == 1 ? d1 : d2);
  int j = (blockIdx.x * blockDim.x + threadIdx.x) * 4;  // grid covers F*D exactly
  float4 v = *(const float4*)(in + j);
  out[j + 0] = __float2bfloat16(v.x);
  out[j + 1] = __float2bfloat16(v.y);
  out[j + 2] = __float2bfloat16(v.z);
  out[j + 3] = __float2bfloat16(v.w);
}

// in: fp32 [R][C] (+z*R*C) -> out: bf16 [C][R] (+z*R*C)
__global__ void k_transpose(const float* __restrict__ in, __hip_bfloat16* __restrict__ out,
                            int R, int C) {
  __shared__ __hip_bfloat16 tile[64][66];
  size_t zofs = (size_t)blockIdx.z * R * C;
  in += zofs; out += zofs;
  int r0 = blockIdx.y * 64, c0 = blockIdx.x * 64;
  int rr = threadIdx.x >> 6;
  int cc = threadIdx.x & 63;
#pragma unroll
  for (int i = 0; i < 16; i++) {
    int r = i * 4 + rr;
    tile[r][cc] = __float2bfloat16(in[(size_t)(r0 + r) * C + c0 + cc]);
  }
  __syncthreads();
#pragma unroll
  for (int i = 0; i < 16; i++) {
    int c = i * 4 + rr;
    out[(size_t)(c0 + c) * R + r0 + cc] = tile[cc][c];
  }
}

// ---------------- router ----------------
__global__ void k_router(const float* __restrict__ x, const float* __restrict__ rw,
                         __hip_bfloat16* __restrict__ xbf, int* __restrict__ counts,
                         int* __restrict__ top_e, float* __restrict__ top_g) {
  int t = blockIdx.x * 4 + (threadIdx.x >> 6);
  int l = threadIdx.x & 63;
  const float* xr = x + (size_t)t * DDIM;
  float acc[NEXP];
#pragma unroll
  for (int e = 0; e < NEXP; e++) acc[e] = 0.f;
#pragma unroll
  for (int i = 0; i < 16; i++) {
    int d = i * 64 + l;
    float v = xr[d];
    xbf[(size_t)t * DDIM + d] = __float2bfloat16(v);
    const float* rr = rw + (size_t)d * NEXP;
#pragma unroll
    for (int e = 0; e < NEXP; e++) acc[e] += v * rr[e];
  }
#pragma unroll
  for (int e = 0; e < NEXP; e++) {
#pragma unroll
    for (int s = 32; s > 0; s >>= 1) acc[e] += __shfl_xor(acc[e], s);
  }
  if (l == 0) {
    float b1 = -1e30f, b2 = -1e30f;
    int i1 = 0, i2 = 0;
#pragma unroll
    for (int e = 0; e < NEXP; e++) {
      float v = acc[e];
      if (v > b1) { b2 = b1; i2 = i1; b1 = v; i1 = e; }
      else if (v > b2) { b2 = v; i2 = e; }
    }
    atomicAdd(&counts[i1], 1);
    atomicAdd(&counts[i2], 1);
    top_e[t * 2 + 0] = i1; top_e[t * 2 + 1] = i2;
    top_g[t * 2 + 0] = sigmoidf_(b1); top_g[t * 2 + 1] = sigmoidf_(b2);
  }
}

__global__ void k_scan(int* __restrict__ counts, int* __restrict__ offs,
                       int* __restrict__ cursor) {
  if (threadIdx.x == 0 && blockIdx.x == 0) {
    counts[NEXP] = A_TOK;  // shared pseudo-expert
    int s = 0;
    for (int e = 0; e < NE9; e++) { offs[e] = s; s += counts[e]; cursor[e] = 0; }
  }
}

__global__ void k_dispatch(const float* __restrict__ x, const int* __restrict__ top_e,
                           const float* __restrict__ top_g, const int* __restrict__ offs,
                           int* __restrict__ cursor, int* __restrict__ slot_of,
                           __hip_bfloat16* __restrict__ y) {
  int t = blockIdx.x * 4 + (threadIdx.x >> 6);
  int l = threadIdx.x & 63;
  int e0 = top_e[t * 2 + 0], e1 = top_e[t * 2 + 1];
  float g0 = top_g[t * 2 + 0], g1 = top_g[t * 2 + 1];
  int s0 = 0, s1 = 0;
  if (l == 0) {
    s0 = offs[e0] + atomicAdd(&cursor[e0], 1);
    s1 = offs[e1] + atomicAdd(&cursor[e1], 1);
    slot_of[t * 2 + 0] = s0; slot_of[t * 2 + 1] = s1;
  }
  s0 = __shfl(s0, 0); s1 = __shfl(s1, 0);
  const float* xr = x + (size_t)t * DDIM;
#pragma unroll
  for (int i = 0; i < 16; i++) {
    int d = i * 64 + l;
    float v = xr[d];
    y[(size_t)s0 * DDIM + d] = __float2bfloat16(v * g0);
    y[(size_t)s1 * DDIM + d] = __float2bfloat16(v * g1);
  }
}

// ------- fused in+swiglu grouped GEMM: h = silu(A@B1^T) * (A@B2^T), bf16 out -------
// A: bf16 [6144][D] (y_all ++ xbf), B1/B2: bf16 [9][F][D], O: bf16 [6144][F]
__global__ __launch_bounds__(256, 2) void k_in_swiglu(
    const ushort* __restrict__ Abase, const ushort* __restrict__ B1base,
    const ushort* __restrict__ B2base, ushort* __restrict__ Obase,
    const int* __restrict__ d_cnt, const int* __restrict__ d_off) {
  int e = blockIdx.z;
  int cnt = d_cnt[e];
  int m0 = blockIdx.y * BM;
  if (m0 >= cnt) return;
  int roff = d_off[e];
  int n0 = blockIdx.x * BN;
  const char* B1 = (const char*)(B1base + (size_t)e * FDIM * DDIM);
  const char* B2 = (const char*)(B2base + (size_t)e * FDIM * DDIM);

  __shared__ __align__(16) ushort sA[BM * BK];
  __shared__ __align__(16) ushort sB1[BN * BK];
  __shared__ __align__(16) ushort sB2[BN * BK];

  int tid = threadIdx.x;
  int w = tid >> 6, l = tid & 63;
  int wm = w >> 1, wn = w & 1;
  int lr = l & 15, kg = l >> 4;

  f32x4 acc1[4][4], acc2[4][4];
#pragma unroll
  for (int i = 0; i < 4; i++)
#pragma unroll
    for (int j = 0; j < 4; j++) {
      acc1[i][j] = {0.f, 0.f, 0.f, 0.f};
      acc2[i][j] = {0.f, 0.f, 0.f, 0.f};
    }

  size_t arow0 = (size_t)roff + m0;
  for (int k0 = 0; k0 < DDIM; k0 += BK) {
    __syncthreads();
#pragma unroll
    for (int t2 = 0; t2 < 2; t2++) {
      int ofs = (tid + t2 * 256) * 16;
      int row = ofs >> 6, inb = ofs & 63;
      lds16((const char*)Abase + (((arow0 + row) * (size_t)DDIM + k0) << 1) + inb, (char*)sA + ofs);
      lds16(B1 + (((size_t)(n0 + row) * DDIM + k0) << 1) + inb, (char*)sB1 + ofs);
      lds16(B2 + (((size_t)(n0 + row) * DDIM + k0) << 1) + inb, (char*)sB2 + ofs);
    }
    __syncthreads();
    short8v af[4];
#pragma unroll
    for (int im = 0; im < 4; im++)
      af[im] = *(const short8v*)&sA[(wm * 64 + im * 16 + lr) * BK + kg * 8];
#pragma unroll
    for (int in = 0; in < 4; in++) {
      short8v b1f = *(const short8v*)&sB1[(wn * 64 + in * 16 + lr) * BK + kg * 8];
      short8v b2f = *(const short8v*)&sB2[(wn * 64 + in * 16 + lr) * BK + kg * 8];
#pragma unroll
      for (int im = 0; im < 4; im++) {
        acc1[im][in] = __builtin_amdgcn_mfma_f32_16x16x32_bf16(af[im], b1f, acc1[im][in], 0, 0, 0);
        acc2[im][in] = __builtin_amdgcn_mfma_f32_16x16x32_bf16(af[im], b2f, acc2[im][in], 0, 0, 0);
      }
    }
  }
#pragma unroll
  for (int im = 0; im < 4; im++)
#pragma unroll
    for (int in = 0; in < 4; in++)
#pragma unroll
      for (int r = 0; r < 4; r++) {
        int row = m0 + wm * 64 + im * 16 + kg * 4 + r;
        if (row < cnt) {
          float mid = acc1[im][in][r];
          float sw = acc2[im][in][r];
          float h = mid * sigmoidf_(mid) * sw;
          int col = n0 + wn * 64 + in * 16 + lr;
          __hip_bfloat16 hb = __float2bfloat16(h);
          ushort u; __builtin_memcpy(&u, &hb, 2);
          Obase[((size_t)roff + row) * FDIM + col] = u;
        }
      }
}

// ------- out-proj grouped GEMM, split-K=2, pure stores: part[kz] = A@B^T -------
// A: bf16 [6144][F] (h), B: bf16 [9][D][F], out: fp32 [2][6144][D]
__global__ __launch_bounds__(256, 2) void k_out(
    const ushort* __restrict__ Abase, const ushort* __restrict__ Bbase,
    float* __restrict__ part, const int* __restrict__ d_cnt, const int* __restrict__ d_off) {
  int e = blockIdx.z;
  int cnt = d_cnt[e];
  int mt = blockIdx.y >> 1, kz = blockIdx.y & 1;
  int m0 = mt * BM;
  if (m0 >= cnt) return;
  int roff = d_off[e];
  int n0 = blockIdx.x * BN;
  const char* B = (const char*)(Bbase + (size_t)e * DDIM * FDIM);

  __shared__ __align__(16) ushort sA[BM * BK];
  __shared__ __align__(16) ushort sB[BN * BK];

  int tid = threadIdx.x;
  int w = tid >> 6, l = tid & 63;
  int wm = w >> 1, wn = w & 1;
  int lr = l & 15, kg = l >> 4;

  f32x4 acc[4][4];
#pragma unroll
  for (int i = 0; i < 4; i++)
#pragma unroll
    for (int j = 0; j < 4; j++) acc[i][j] = {0.f, 0.f, 0.f, 0.f};

  size_t arow0 = (size_t)roff + m0;
  int kbeg = kz * (FDIM / 2), kend = kbeg + FDIM / 2;
  for (int k0 = kbeg; k0 < kend; k0 += BK) {
    __syncthreads();
#pragma unroll
    for (int t2 = 0; t2 < 2; t2++) {
      int ofs = (tid + t2 * 256) * 16;
      int row = ofs >> 6, inb = ofs & 63;
      lds16((const char*)Abase + (((arow0 + row) * (size_t)FDIM + k0) << 1) + inb, (char*)sA + ofs);
      lds16(B + (((size_t)(n0 + row) * FDIM + k0) << 1) + inb, (char*)sB + ofs);
    }
    __syncthreads();
    short8v af[4];
#pragma unroll
    for (int im = 0; im < 4; im++)
      af[im] = *(const short8v*)&sA[(wm * 64 + im * 16 + lr) * BK + kg * 8];
#pragma unroll
    for (int in = 0; in < 4; in++) {
      short8v bf = *(const short8v*)&sB[(wn * 64 + in * 16 + lr) * BK + kg * 8];
#pragma unroll
      for (int im = 0; im < 4; im++)
        acc[im][in] = __builtin_amdgcn_mfma_f32_16x16x32_bf16(af[im], bf, acc[im][in], 0, 0, 0);
    }
  }
  float* outp = part + (size_t)kz * SLOTS_T * DDIM;
#pragma unroll
  for (int im = 0; im < 4; im++)
#pragma unroll
    for (int in = 0; in < 4; in++)
#pragma unroll
      for (int r = 0; r < 4; r++) {
        int row = m0 + wm * 64 + im * 16 + kg * 4 + r;
        if (row < cnt) {
          int col = n0 + wn * 64 + in * 16 + lr;
          outp[((size_t)roff + row) * DDIM + col] = acc[im][in][r];
        }
      }
}

// ------- combine: out[t] = sum_kz part[kz][s0] + part[kz][s1] + part[kz][4096+t] -------
__global__ void k_combine(const float* __restrict__ part, const int* __restrict__ slot_of,
                          float* __restrict__ out) {
  int t = blockIdx.x;
  int d4 = threadIdx.x;  // 256 float4 per 1024-dim row
  int s0 = slot_of[t * 2 + 0], s1 = slot_of[t * 2 + 1];
  const float4* p0 = (const float4*)part;
  const float4* p1 = (const float4*)(part + (size_t)SLOTS_T * DDIM);
  size_t rq = DDIM / 4;
  float4 a = p0[(size_t)s0 * rq + d4];
  float4 b = p0[(size_t)s1 * rq + d4];
  float4 c = p0[((size_t)SLOTS_R + t) * rq + d4];
  float4 d = p1[(size_t)s0 * rq + d4];
  float4 e = p1[(size_t)s1 * rq + d4];
  float4 f = p1[((size_t)SLOTS_R + t) * rq + d4];
  float4 o;
  o.x = a.x + b.x + c.x + d.x + e.x + f.x;
  o.y = a.y + b.y + c.y + d.y + e.y + f.y;
  o.z = a.z + b.z + c.z + d.z + e.z + f.z;
  o.w = a.w + b.w + c.w + d.w + e.w + f.w;
  ((float4*)out)[(size_t)t * rq + d4] = o;
}

extern "C" void kernel_launch(void* const* d_in, const int* in_sizes, int n_in,
                              void* d_out, int out_size, void* d_ws, size_t ws_size,
                              hipStream_t stream) {
  (void)in_sizes; (void)n_in; (void)out_size; (void)ws_size;
  const float* x        = (const float*)d_in[0];
  const float* router   = (const float*)d_in[1];
  const float* w_in_sh  = (const float*)d_in[2];
  const float* w_out_sh = (const float*)d_in[3];
  const float* w_sw_sh  = (const float*)d_in[4];
  const float* w_in_e   = (const float*)d_in[5];
  const float* w_sw_e   = (const float*)d_in[6];
  const float* w_out_e  = (const float*)d_in[7];
  float* out = (float*)d_out;

  char* ws = (char*)d_ws;
  size_t off = 0;
  auto alloc = [&](size_t bytes) -> char* {
    char* p = ws + off;
    off += (bytes + 255) & ~(size_t)255;
    return p;
  };
  // Buffer order matters:
  //  - y_all (4096 rows) and xbf (2048 rows) are contiguous -> one A matrix of 6144 rows
  //    (shared expert = pseudo-expert 8 with gate 1). Partial-tile A overreads land in
  //    the next region (valid memory; stores are count-guarded).
  //  - slot_part ALIASES wt_in_t/wt_sw_t: those weights are dead after k_in_swiglu,
  //    and k_out (which writes slot_part) only reads wt_out_t + h. Saves 50 MB of ws.
  __hip_bfloat16* wt_in_t  = (__hip_bfloat16*)alloc((size_t)NE9 * FDIM * DDIM * 2);  // [9][F][D]
  __hip_bfloat16* wt_sw_t  = (__hip_bfloat16*)alloc((size_t)NE9 * FDIM * DDIM * 2);  // [9][F][D]
  __hip_bfloat16* wt_out_t = (__hip_bfloat16*)alloc((size_t)NE9 * DDIM * FDIM * 2);  // [9][D][F]
  __hip_bfloat16* y_all    = (__hip_bfloat16*)alloc((size_t)SLOTS_R * DDIM * 2);
  __hip_bfloat16* xbf      = (__hip_bfloat16*)alloc((size_t)A_TOK * DDIM * 2);  // contiguous after y_all
  __hip_bfloat16* h        = (__hip_bfloat16*)alloc((size_t)SLOTS_T * FDIM * 2);
  int*   counts  = (int*)alloc(64);
  int*   offs    = (int*)alloc(64);
  int*   cursor  = (int*)alloc(64);
  int*   top_e   = (int*)alloc((size_t)A_TOK * 2 * 4);
  float* top_g   = (float*)alloc((size_t)A_TOK * 2 * 4);
  int*   slot_of = (int*)alloc((size_t)A_TOK * 2 * 4);
  float* slot_part = (float*)wt_in_t;  // [2][6144][1024] fp32 = 50.3 MB <= 75.5 MB alias region

  hipMemsetAsync(counts, 0, 64, stream);

  // weight prep
  k_cvt3<<<dim3((FDIM * DDIM / 4) / 256, 1, 3), 256, 0, stream>>>(
      w_in_sh, w_sw_sh, w_out_sh,
      wt_in_t + (size_t)NEXP * FDIM * DDIM,
      wt_sw_t + (size_t)NEXP * FDIM * DDIM,
      wt_out_t + (size_t)NEXP * DDIM * FDIM);
  k_transpose<<<dim3(FDIM / 64, DDIM / 64, NEXP), 256, 0, stream>>>(w_in_e, wt_in_t, DDIM, FDIM);
  k_transpose<<<dim3(FDIM / 64, DDIM / 64, NEXP), 256, 0, stream>>>(w_sw_e, wt_sw_t, DDIM, FDIM);
  k_transpose<<<dim3(DDIM / 64, FDIM / 64, NEXP), 256, 0, stream>>>(w_out_e, wt_out_t, FDIM, DDIM);

  // routing
  k_router<<<dim3(A_TOK / 4), 256, 0, stream>>>(x, router, xbf, counts, top_e, top_g);
  k_scan<<<1, 64, 0, stream>>>(counts, offs, cursor);
  k_dispatch<<<dim3(A_TOK / 4), 256, 0, stream>>>(x, top_e, top_g, offs, cursor, slot_of, y_all);

  // grouped in+swiglu over all 9 experts: M=6144 total, N=F, K=D
  k_in_swiglu<<<dim3(FDIM / BN, A_TOK / BM, NE9), 256, 0, stream>>>(
      (const ushort*)y_all, (const ushort*)wt_in_t, (const ushort*)wt_sw_t,
      (ushort*)h, counts, offs);

  // grouped out-proj, split-K=2: N=D, K=F/2 per block
  k_out<<<dim3(DDIM / BN, (A_TOK / BM) * 2, NE9), 256, 0, stream>>>(
      (const ushort*)h, (const ushort*)wt_out_t, slot_part, counts, offs);

  // combine (fully overwrites d_out -> poison-safe)
  k_combine<<<dim3(A_TOK), 256, 0, stream>>>(slot_part, slot_of, out);
}

// Round 3
// 307.455 us; speedup vs baseline: 1.4517x; 1.0301x over previous
//
#include <hip/hip_runtime.h>
#include <hip/hip_bf16.h>

#define A_TOK 2048
#define DDIM 1024
#define FDIM 2048
#define NEXP 8
#define NE9 9                      // 8 routed + 1 shared pseudo-expert
#define SLOTS_R (2 * A_TOK)        // 4096 routed slots
#define SLOTS_T (SLOTS_R + A_TOK)  // 6144 incl. shared rows

typedef __attribute__((ext_vector_type(8))) short short8v;  // 8 bf16 (4 VGPR)
typedef __attribute__((ext_vector_type(4))) float f32x4;

#define BARRIER() asm volatile("s_barrier" ::: "memory")
#define VMCNT(n) asm volatile("s_waitcnt vmcnt(" #n ")" ::: "memory")

__device__ __forceinline__ void lds16(const void* g, void* l) {
  __builtin_amdgcn_global_load_lds((const __attribute__((address_space(1))) void*)g,
                                   (__attribute__((address_space(3))) void*)l, 16, 0, 0);
}

__device__ __forceinline__ float sigmoidf_(float x) { return 1.f / (1.f + __expf(-x)); }

// Stage one 8KB unit (128 rows x 32 bf16) global->LDS with granule swizzle:
// LDS slot (row, g) holds global granule g ^ ((row>>1)&3). gload_lds dest is
// linear (rule: can't swizzle the LDS side); the swizzle lives in the per-lane
// GLOBAL address + the frag-read address (same involution both sides).
__device__ __forceinline__ void stage_unit(const ushort* gbase, size_t grow0,
                                           int K, int k0, char* lds, int tid) {
  int o = tid * 16;
  int row = o >> 6;            // 0..127 (unit-local; swizzle fn is mod-4 safe across units)
  int g = (o >> 4) & 3;        // 16B granule within 64B row
  int gg = g ^ ((row >> 1) & 3);
  lds16((const char*)(gbase + (grow0 + row) * (size_t)K + k0 + gg * 8), lds + o);
}

// ---------------- weight prep ----------------
__global__ void k_cvt3(const float* __restrict__ s0, const float* __restrict__ s1,
                       const float* __restrict__ s2, __hip_bfloat16* __restrict__ d0,
                       __hip_bfloat16* __restrict__ d1, __hip_bfloat16* __restrict__ d2) {
  const float* in = blockIdx.z == 0 ? s0 : (blockIdx.z == 1 ? s1 : s2);
  __hip_bfloat16* out = blockIdx.z == 0 ? d0 : (blockIdx.z == 1 ? d1 : d2);
  int j = (blockIdx.x * blockDim.x + threadIdx.x) * 4;
  float4 v = *(const float4*)(in + j);
  out[j + 0] = __float2bfloat16(v.x);
  out[j + 1] = __float2bfloat16(v.y);
  out[j + 2] = __float2bfloat16(v.z);
  out[j + 3] = __float2bfloat16(v.w);
}

// in: fp32 [R][C] (+z*R*C) -> out: bf16 [C][R] (+z*R*C)
__global__ void k_transpose(const float* __restrict__ in, __hip_bfloat16* __restrict__ out,
                            int R, int C) {
  __shared__ __hip_bfloat16 tile[64][66];
  size_t zofs = (size_t)blockIdx.z * R * C;
  in += zofs; out += zofs;
  int r0 = blockIdx.y * 64, c0 = blockIdx.x * 64;
  int rr = threadIdx.x >> 6;
  int cc = threadIdx.x & 63;
#pragma unroll
  for (int i = 0; i < 16; i++) {
    int r = i * 4 + rr;
    tile[r][cc] = __float2bfloat16(in[(size_t)(r0 + r) * C + c0 + cc]);
  }
  __syncthreads();
#pragma unroll
  for (int i = 0; i < 16; i++) {
    int c = i * 4 + rr;
    out[(size_t)(c0 + c) * R + r0 + cc] = tile[cc][c];
  }
}

// ---------------- router ----------------
__global__ void k_router(const float* __restrict__ x, const float* __restrict__ rw,
                         __hip_bfloat16* __restrict__ xbf, int* __restrict__ counts,
                         int* __restrict__ top_e, float* __restrict__ top_g) {
  int t = blockIdx.x * 4 + (threadIdx.x >> 6);
  int l = threadIdx.x & 63;
  const float* xr = x + (size_t)t * DDIM;
  float acc[NEXP];
#pragma unroll
  for (int e = 0; e < NEXP; e++) acc[e] = 0.f;
#pragma unroll
  for (int i = 0; i < 16; i++) {
    int d = i * 64 + l;
    float v = xr[d];
    xbf[(size_t)t * DDIM + d] = __float2bfloat16(v);
    const float* rr = rw + (size_t)d * NEXP;
#pragma unroll
    for (int e = 0; e < NEXP; e++) acc[e] += v * rr[e];
  }
#pragma unroll
  for (int e = 0; e < NEXP; e++) {
#pragma unroll
    for (int s = 32; s > 0; s >>= 1) acc[e] += __shfl_xor(acc[e], s);
  }
  if (l == 0) {
    float b1 = -1e30f, b2 = -1e30f;
    int i1 = 0, i2 = 0;
#pragma unroll
    for (int e = 0; e < NEXP; e++) {
      float v = acc[e];
      if (v > b1) { b2 = b1; i2 = i1; b1 = v; i1 = e; }
      else if (v > b2) { b2 = v; i2 = e; }
    }
    atomicAdd(&counts[i1], 1);
    atomicAdd(&counts[i2], 1);
    top_e[t * 2 + 0] = i1; top_e[t * 2 + 1] = i2;
    top_g[t * 2 + 0] = sigmoidf_(b1); top_g[t * 2 + 1] = sigmoidf_(b2);
  }
}

__global__ void k_scan(int* __restrict__ counts, int* __restrict__ offs,
                       int* __restrict__ cursor) {
  if (threadIdx.x == 0 && blockIdx.x == 0) {
    counts[NEXP] = A_TOK;  // shared pseudo-expert
    int s = 0;
    for (int e = 0; e < NE9; e++) { offs[e] = s; s += counts[e]; cursor[e] = 0; }
  }
}

__global__ void k_dispatch(const float* __restrict__ x, const int* __restrict__ top_e,
                           const float* __restrict__ top_g, const int* __restrict__ offs,
                           int* __restrict__ cursor, int* __restrict__ slot_of,
                           __hip_bfloat16* __restrict__ y) {
  int t = blockIdx.x * 4 + (threadIdx.x >> 6);
  int l = threadIdx.x & 63;
  int e0 = top_e[t * 2 + 0], e1 = top_e[t * 2 + 1];
  float g0 = top_g[t * 2 + 0], g1 = top_g[t * 2 + 1];
  int s0 = 0, s1 = 0;
  if (l == 0) {
    s0 = offs[e0] + atomicAdd(&cursor[e0], 1);
    s1 = offs[e1] + atomicAdd(&cursor[e1], 1);
    slot_of[t * 2 + 0] = s0; slot_of[t * 2 + 1] = s1;
  }
  s0 = __shfl(s0, 0); s1 = __shfl(s1, 0);
  const float* xr = x + (size_t)t * DDIM;
#pragma unroll
  for (int i = 0; i < 16; i++) {
    int d = i * 64 + l;
    float v = xr[d];
    y[(size_t)s0 * DDIM + d] = __float2bfloat16(v * g0);
    y[(size_t)s1 * DDIM + d] = __float2bfloat16(v * g1);
  }
}

// ======== fused in+swiglu grouped GEMM, counted-vmcnt phase schedule ========
// h = silu(A@B1^T) * (A@B2^T). A: bf16 [6144][D], B1/B2: bf16 [9][F][D], O: bf16 [6144][F].
// BM=128 BN=256 BK=32, 8 waves (2Mx4N), wave tile 64x64 per B-operand.
// 3 rotating LDS K-tile buffers (A 8K | B1 16K | B2 16K = 40KB each, 120KB total).
// K-tile t computes from buf[t%3] while issuing stages of t+2 into buf[(t+2)%3];
// boundary wait = vmcnt(5) (the 5 units of t+2 stay in flight) — never 0 mid-loop.
__global__ __launch_bounds__(512, 2) void k_mlp1(
    const ushort* __restrict__ Abase, const ushort* __restrict__ B1base,
    const ushort* __restrict__ B2base, ushort* __restrict__ Obase,
    const int* __restrict__ d_cnt, const int* __restrict__ d_off) {
  constexpr int K = DDIM, NT = DDIM / 32;
  constexpr int BUF = 40960;
  __shared__ __align__(16) char smem[3 * BUF];
  int e = blockIdx.z;
  int cnt = d_cnt[e];
  int m0 = blockIdx.y * 128;
  if (m0 >= cnt) return;
  int roff = d_off[e];
  int n0 = blockIdx.x * 256;
  const ushort* B1 = B1base + (size_t)e * FDIM * DDIM;
  const ushort* B2 = B2base + (size_t)e * FDIM * DDIM;
  int tid = threadIdx.x;
  int w = tid >> 6, l = tid & 63;
  int wm = w >> 2, wn = w & 3;
  int lr = l & 15, kg = l >> 4;
  size_t arow0 = (size_t)roff + m0;

  f32x4 acc1[4][4], acc2[4][4];
#pragma unroll
  for (int i = 0; i < 4; i++)
#pragma unroll
    for (int j = 0; j < 4; j++) {
      acc1[i][j] = {0.f, 0.f, 0.f, 0.f};
      acc2[i][j] = {0.f, 0.f, 0.f, 0.f};
    }

  auto frag = [&](const char* base, int row) -> short8v {
    return *(const short8v*)(base + row * 64 + ((kg ^ ((row >> 1) & 3)) << 4));
  };

  // prologue: fully stage K-tiles 0,1 (issue order per K-tile == loop order)
#pragma unroll
  for (int pt = 0; pt < 2; ++pt) {
    char* bb = smem + pt * BUF;
    int k0 = pt * 32;
    stage_unit(Abase, arow0, K, k0, bb, tid);
    stage_unit(B1, (size_t)n0, K, k0, bb + 8192, tid);
    stage_unit(B1, (size_t)n0 + 128, K, k0, bb + 16384, tid);
    stage_unit(B2, (size_t)n0, K, k0, bb + 24576, tid);
    stage_unit(B2, (size_t)n0 + 128, K, k0, bb + 32768, tid);
  }
  VMCNT(5);  // 10 in flight -> oldest 5 (= K-tile 0) done
  BARRIER();

  char* b0 = smem;
  char* b1 = smem + BUF;
  char* b2 = smem + 2 * BUF;
  for (int t = 0; t < NT; ++t) {
    bool st = (t + 2) < NT;
    int k2 = (t + 2) * 32;
    short8v af[4], bf[4];
    // ---- phase 0: A + B1 frags, stage units 0-1 of t+2, MFMA acc1 ----
#pragma unroll
    for (int mf = 0; mf < 4; mf++) af[mf] = frag(b0, wm * 64 + mf * 16 + lr);
#pragma unroll
    for (int nf = 0; nf < 4; nf++) bf[nf] = frag(b0 + 8192, wn * 64 + nf * 16 + lr);
    if (st) {
      stage_unit(Abase, arow0, K, k2, b2, tid);
      stage_unit(B1, (size_t)n0, K, k2, b2 + 8192, tid);
    }
    BARRIER();
    __builtin_amdgcn_s_setprio(1);
#pragma unroll
    for (int nf = 0; nf < 4; nf++)
#pragma unroll
      for (int mf = 0; mf < 4; mf++)
        acc1[mf][nf] = __builtin_amdgcn_mfma_f32_16x16x32_bf16(af[mf], bf[nf], acc1[mf][nf], 0, 0, 0);
    __builtin_amdgcn_s_setprio(0);
    BARRIER();
    // ---- phase 1: B2 frags, stage units 2-4 of t+2, MFMA acc2 ----
#pragma unroll
    for (int nf = 0; nf < 4; nf++) bf[nf] = frag(b0 + 24576, wn * 64 + nf * 16 + lr);
    if (st) {
      stage_unit(B1, (size_t)n0 + 128, K, k2, b2 + 16384, tid);
      stage_unit(B2, (size_t)n0, K, k2, b2 + 24576, tid);
      stage_unit(B2, (size_t)n0 + 128, K, k2, b2 + 32768, tid);
    }
    BARRIER();
    __builtin_amdgcn_s_setprio(1);
#pragma unroll
    for (int nf = 0; nf < 4; nf++)
#pragma unroll
      for (int mf = 0; mf < 4; mf++)
        acc2[mf][nf] = __builtin_amdgcn_mfma_f32_16x16x32_bf16(af[mf], bf[nf], acc2[mf][nf], 0, 0, 0);
    __builtin_amdgcn_s_setprio(0);
    // ---- K-tile boundary: counted wait (t+1's units retired; t+2's stay in flight)
    if (t < NT - 1) {
      if (st) { VMCNT(5); } else { VMCNT(0); }
      BARRIER();
    }
    char* tmp = b0; b0 = b1; b1 = b2; b2 = tmp;
  }

#pragma unroll
  for (int mf = 0; mf < 4; mf++)
#pragma unroll
    for (int nf = 0; nf < 4; nf++)
#pragma unroll
      for (int r = 0; r < 4; r++) {
        int row = m0 + wm * 64 + mf * 16 + kg * 4 + r;
        if (row < cnt) {
          float mid = acc1[mf][nf][r];
          float sw = acc2[mf][nf][r];
          float h = mid * sigmoidf_(mid) * sw;
          int col = n0 + wn * 64 + nf * 16 + lr;
          __hip_bfloat16 hb = __float2bfloat16(h);
          ushort u; __builtin_memcpy(&u, &hb, 2);
          Obase[((size_t)roff + row) * FDIM + col] = u;
        }
      }
}

// ======== out-proj grouped GEMM, split-K=2, same counted-vmcnt schedule ========
// part[kz] = A@B^T. A: bf16 [6144][F], B: bf16 [9][D][F], part: fp32 [2][6144][D].
// Buffer = A 8K | B 16K = 24KB, x3 = 72KB -> 2 blocks/CU.
__global__ __launch_bounds__(512, 4) void k_mlp2(
    const ushort* __restrict__ Abase, const ushort* __restrict__ Bbase,
    float* __restrict__ part, const int* __restrict__ d_cnt, const int* __restrict__ d_off) {
  constexpr int K = FDIM, NT = 1024 / 32;  // 1024 K per split
  constexpr int BUF = 24576;
  __shared__ __align__(16) char smem[3 * BUF];
  int e = blockIdx.z;
  int cnt = d_cnt[e];
  int mt = blockIdx.y >> 1, kz = blockIdx.y & 1;
  int m0 = mt * 128;
  if (m0 >= cnt) return;
  int roff = d_off[e];
  int n0 = blockIdx.x * 256;
  int kbeg = kz * 1024;
  const ushort* B = Bbase + (size_t)e * DDIM * FDIM;
  int tid = threadIdx.x;
  int w = tid >> 6, l = tid & 63;
  int wm = w >> 2, wn = w & 3;
  int lr = l & 15, kg = l >> 4;
  size_t arow0 = (size_t)roff + m0;

  f32x4 acc[4][4];
#pragma unroll
  for (int i = 0; i < 4; i++)
#pragma unroll
    for (int j = 0; j < 4; j++) acc[i][j] = {0.f, 0.f, 0.f, 0.f};

  auto frag = [&](const char* base, int row) -> short8v {
    return *(const short8v*)(base + row * 64 + ((kg ^ ((row >> 1) & 3)) << 4));
  };

#pragma unroll
  for (int pt = 0; pt < 2; ++pt) {
    char* bb = smem + pt * BUF;
    int k0 = kbeg + pt * 32;
    stage_unit(Abase, arow0, K, k0, bb, tid);
    stage_unit(B, (size_t)n0, K, k0, bb + 8192, tid);
    stage_unit(B, (size_t)n0 + 128, K, k0, bb + 16384, tid);
  }
  VMCNT(3);
  BARRIER();

  char* b0 = smem;
  char* b1 = smem + BUF;
  char* b2 = smem + 2 * BUF;
  for (int t = 0; t < NT; ++t) {
    bool st = (t + 2) < NT;
    int k2 = kbeg + (t + 2) * 32;
    short8v af[4], bf[4];
    // ---- phase 0 ----
#pragma unroll
    for (int mf = 0; mf < 4; mf++) af[mf] = frag(b0, wm * 64 + mf * 16 + lr);
#pragma unroll
    for (int nf = 0; nf < 4; nf++) bf[nf] = frag(b0 + 8192, wn * 64 + nf * 16 + lr);
    if (st) {
      stage_unit(Abase, arow0, K, k2, b2, tid);
      stage_unit(B, (size_t)n0, K, k2, b2 + 8192, tid);
    }
    BARRIER();
    __builtin_amdgcn_s_setprio(1);
#pragma unroll
    for (int nf = 0; nf < 2; nf++)
#pragma unroll
      for (int mf = 0; mf < 4; mf++)
        acc[mf][nf] = __builtin_amdgcn_mfma_f32_16x16x32_bf16(af[mf], bf[nf], acc[mf][nf], 0, 0, 0);
    __builtin_amdgcn_s_setprio(0);
    BARRIER();
    // ---- phase 1 ----
    if (st) stage_unit(B, (size_t)n0 + 128, K, k2, b2 + 16384, tid);
    __builtin_amdgcn_s_setprio(1);
#pragma unroll
    for (int nf = 2; nf < 4; nf++)
#pragma unroll
      for (int mf = 0; mf < 4; mf++)
        acc[mf][nf] = __builtin_amdgcn_mfma_f32_16x16x32_bf16(af[mf], bf[nf], acc[mf][nf], 0, 0, 0);
    __builtin_amdgcn_s_setprio(0);
    if (t < NT - 1) {
      if (st) { VMCNT(3); } else { VMCNT(0); }
      BARRIER();
    }
    char* tmp = b0; b0 = b1; b1 = b2; b2 = tmp;
  }

  float* outp = part + (size_t)kz * SLOTS_T * DDIM;
#pragma unroll
  for (int mf = 0; mf < 4; mf++)
#pragma unroll
    for (int nf = 0; nf < 4; nf++)
#pragma unroll
      for (int r = 0; r < 4; r++) {
        int row = m0 + wm * 64 + mf * 16 + kg * 4 + r;
        if (row < cnt) {
          int col = n0 + wn * 64 + nf * 16 + lr;
          outp[((size_t)roff + row) * DDIM + col] = acc[mf][nf][r];
        }
      }
}

// ------- combine: out[t] = sum_kz part[kz][s0] + part[kz][s1] + part[kz][4096+t] -------
__global__ void k_combine(const float* __restrict__ part, const int* __restrict__ slot_of,
                          float* __restrict__ out) {
  int t = blockIdx.x;
  int d4 = threadIdx.x;
  int s0 = slot_of[t * 2 + 0], s1 = slot_of[t * 2 + 1];
  const float4* p0 = (const float4*)part;
  const float4* p1 = (const float4*)(part + (size_t)SLOTS_T * DDIM);
  size_t rq = DDIM / 4;
  float4 a = p0[(size_t)s0 * rq + d4];
  float4 b = p0[(size_t)s1 * rq + d4];
  float4 c = p0[((size_t)SLOTS_R + t) * rq + d4];
  float4 d = p1[(size_t)s0 * rq + d4];
  float4 e = p1[(size_t)s1 * rq + d4];
  float4 f = p1[((size_t)SLOTS_R + t) * rq + d4];
  float4 o;
  o.x = a.x + b.x + c.x + d.x + e.x + f.x;
  o.y = a.y + b.y + c.y + d.y + e.y + f.y;
  o.z = a.z + b.z + c.z + d.z + e.z + f.z;
  o.w = a.w + b.w + c.w + d.w + e.w + f.w;
  ((float4*)out)[(size_t)t * rq + d4] = o;
}

extern "C" void kernel_launch(void* const* d_in, const int* in_sizes, int n_in,
                              void* d_out, int out_size, void* d_ws, size_t ws_size,
                              hipStream_t stream) {
  (void)in_sizes; (void)n_in; (void)out_size; (void)ws_size;
  const float* x        = (const float*)d_in[0];
  const float* router   = (const float*)d_in[1];
  const float* w_in_sh  = (const float*)d_in[2];
  const float* w_out_sh = (const float*)d_in[3];
  const float* w_sw_sh  = (const float*)d_in[4];
  const float* w_in_e   = (const float*)d_in[5];
  const float* w_sw_e   = (const float*)d_in[6];
  const float* w_out_e  = (const float*)d_in[7];
  float* out = (float*)d_out;

  char* ws = (char*)d_ws;
  size_t off = 0;
  auto alloc = [&](size_t bytes) -> char* {
    char* p = ws + off;
    off += (bytes + 255) & ~(size_t)255;
    return p;
  };
  // Ordering: y_all ++ xbf contiguous => one 6144-row A (shared = pseudo-expert 8).
  // slot_part aliases wt_in_t/wt_sw_t (dead after k_mlp1; k_mlp2 reads wt_out_t + h only).
  __hip_bfloat16* wt_in_t  = (__hip_bfloat16*)alloc((size_t)NE9 * FDIM * DDIM * 2);  // [9][F][D]
  __hip_bfloat16* wt_sw_t  = (__hip_bfloat16*)alloc((size_t)NE9 * FDIM * DDIM * 2);  // [9][F][D]
  __hip_bfloat16* wt_out_t = (__hip_bfloat16*)alloc((size_t)NE9 * DDIM * FDIM * 2);  // [9][D][F]
  __hip_bfloat16* y_all    = (__hip_bfloat16*)alloc((size_t)SLOTS_R * DDIM * 2);
  __hip_bfloat16* xbf      = (__hip_bfloat16*)alloc((size_t)A_TOK * DDIM * 2);
  __hip_bfloat16* h        = (__hip_bfloat16*)alloc((size_t)SLOTS_T * FDIM * 2);
  int*   counts  = (int*)alloc(64);
  int*   offs    = (int*)alloc(64);
  int*   cursor  = (int*)alloc(64);
  int*   top_e   = (int*)alloc((size_t)A_TOK * 2 * 4);
  float* top_g   = (float*)alloc((size_t)A_TOK * 2 * 4);
  int*   slot_of = (int*)alloc((size_t)A_TOK * 2 * 4);
  float* slot_part = (float*)wt_in_t;  // [2][6144][1024] fp32 = 50.3 MB alias

  hipMemsetAsync(counts, 0, 64, stream);

  // weight prep
  k_cvt3<<<dim3((FDIM * DDIM / 4) / 256, 1, 3), 256, 0, stream>>>(
      w_in_sh, w_sw_sh, w_out_sh,
      wt_in_t + (size_t)NEXP * FDIM * DDIM,
      wt_sw_t + (size_t)NEXP * FDIM * DDIM,
      wt_out_t + (size_t)NEXP * DDIM * FDIM);
  k_transpose<<<dim3(FDIM / 64, DDIM / 64, NEXP), 256, 0, stream>>>(w_in_e, wt_in_t, DDIM, FDIM);
  k_transpose<<<dim3(FDIM / 64, DDIM / 64, NEXP), 256, 0, stream>>>(w_sw_e, wt_sw_t, DDIM, FDIM);
  k_transpose<<<dim3(DDIM / 64, FDIM / 64, NEXP), 256, 0, stream>>>(w_out_e, wt_out_t, FDIM, DDIM);

  // routing
  k_router<<<dim3(A_TOK / 4), 256, 0, stream>>>(x, router, xbf, counts, top_e, top_g);
  k_scan<<<1, 64, 0, stream>>>(counts, offs, cursor);
  k_dispatch<<<dim3(A_TOK / 4), 256, 0, stream>>>(x, top_e, top_g, offs, cursor, slot_of, y_all);

  // fused in+swiglu over 9 experts: BMx BN = 128x256
  k_mlp1<<<dim3(FDIM / 256, A_TOK / 128, NE9), 512, 0, stream>>>(
      (const ushort*)y_all, (const ushort*)wt_in_t, (const ushort*)wt_sw_t,
      (ushort*)h, counts, offs);

  // out-proj, split-K=2
  k_mlp2<<<dim3(DDIM / 256, (A_TOK / 128) * 2, NE9), 512, 0, stream>>>(
      (const ushort*)h, (const ushort*)wt_out_t, slot_part, counts, offs);

  // combine (fully overwrites d_out -> poison-safe)
  k_combine<<<dim3(A_TOK), 256, 0, stream>>>(slot_part, slot_of, out);
}

// Round 4
// 305.007 us; speedup vs baseline: 1.4634x; 1.0080x over previous
//
#include <hip/hip_runtime.h>
#include <hip/hip_bf16.h>

#define A_TOK 2048
#define DDIM 1024
#define FDIM 2048
#define NEXP 8
#define NE9 9                      // 8 routed + 1 shared pseudo-expert
#define SLOTS_R (2 * A_TOK)        // 4096 routed slots
#define SLOTS_T (SLOTS_R + A_TOK)  // 6144 incl. shared rows
#define NB1 (2 * FDIM)             // 4096: interleaved [w_in | w_swiglu] rows (32-col blocks)

typedef __attribute__((ext_vector_type(8))) short short8v;   // 8 bf16
typedef __attribute__((ext_vector_type(4))) float f32x4;
typedef __attribute__((ext_vector_type(4))) ushort ushort4v;

#define BARRIER() asm volatile("s_barrier" ::: "memory")
#define VMCNT(n) asm volatile("s_waitcnt vmcnt(" #n ")" ::: "memory")

__device__ __forceinline__ void lds16(const void* g, void* l) {
  __builtin_amdgcn_global_load_lds((const __attribute__((address_space(1))) void*)g,
                                   (__attribute__((address_space(3))) void*)l, 16, 0, 0);
}

__device__ __forceinline__ float sigmoidf_(float x) { return 1.f / (1.f + __expf(-x)); }
__device__ __forceinline__ ushort f2bf(float x) {
  __hip_bfloat16 b = __float2bfloat16(x);
  ushort u; __builtin_memcpy(&u, &b, 2); return u;
}
__device__ __forceinline__ float bf2f(ushort u) {
  union { unsigned int i; float f; } x; x.i = (unsigned int)u << 16; return x.f;
}

// Stage one 4KB unit (64 rows x 32 bf16) global->LDS, 256 threads.
// LDS slot (row,g) holds global granule g ^ ((row>>1)&3); linear LDS dest (gload_lds
// constraint), swizzle lives in the per-lane GLOBAL address + matching frag-read addr.
__device__ __forceinline__ void stage64(const ushort* gbase, size_t grow0,
                                        int K, int k0, char* lds, int tid) {
  int o = tid * 16;            // 0..4095
  int row = o >> 6;            // 0..63 (unit-local; swizzle fn mod-4-consistent across units)
  int g = (o >> 4) & 3;
  int gg = g ^ ((row >> 1) & 3);
  lds16((const char*)(gbase + (grow0 + row) * (size_t)K + k0 + gg * 8), lds + o);
}

// ---------------- weight prep ----------------
// routed in/sw transpose-convert with interleaved row remap into wt12[e][4096][1024]:
// original f-row -> rp = (f>>5)*64 + which*32 + (f&31)   (which: 0=w_in, 1=w_swiglu)
__global__ void k_tr12(const float* __restrict__ w_in, const float* __restrict__ w_sw,
                       ushort* __restrict__ wt12) {
  int z = blockIdx.z; int e = z & 7; int which = z >> 3;
  const float* in = (which ? w_sw : w_in) + (size_t)e * DDIM * FDIM;  // [D][F]
  ushort* outb = wt12 + (size_t)e * NB1 * DDIM;
  __shared__ ushort tile[64][66];
  int r0 = blockIdx.y * 64, c0 = blockIdx.x * 64;  // r over D, c over F
  int rr = threadIdx.x >> 6, cc = threadIdx.x & 63;
#pragma unroll
  for (int i = 0; i < 16; i++) {
    int r = i * 4 + rr;
    tile[r][cc] = f2bf(in[(size_t)(r0 + r) * FDIM + c0 + cc]);
  }
  __syncthreads();
#pragma unroll
  for (int i = 0; i < 16; i++) {
    int c = i * 4 + rr;
    int f = c0 + c;
    int rp = ((f >> 5) << 6) + (which << 5) + (f & 31);
    outb[(size_t)rp * DDIM + r0 + cc] = tile[cc][c];
  }
}

// plain transpose-convert: in fp32 [R][C] (+z*R*C) -> out bf16 [C][R] (+z*C*R)
__global__ void k_transpose(const float* __restrict__ in, ushort* __restrict__ out,
                            int R, int C) {
  __shared__ ushort tile[64][66];
  in += (size_t)blockIdx.z * R * C;
  out += (size_t)blockIdx.z * R * C;
  int r0 = blockIdx.y * 64, c0 = blockIdx.x * 64;
  int rr = threadIdx.x >> 6, cc = threadIdx.x & 63;
#pragma unroll
  for (int i = 0; i < 16; i++) {
    int r = i * 4 + rr;
    tile[r][cc] = f2bf(in[(size_t)(r0 + r) * C + c0 + cc]);
  }
  __syncthreads();
#pragma unroll
  for (int i = 0; i < 16; i++) {
    int c = i * 4 + rr;
    out[(size_t)(c0 + c) * R + r0 + cc] = tile[cc][c];
  }
}

// shared weights: w_in_sh/w_sw_sh [F][D] -> wt12[8] rows (remap, no transpose needed);
// w_out_sh [D][F] -> wt_out_t[8] rows (plain convert)
__global__ void k_cvt_sh(const float* __restrict__ w_in_sh, const float* __restrict__ w_sw_sh,
                         const float* __restrict__ w_out_sh, ushort* __restrict__ wt12_8,
                         ushort* __restrict__ wtout_8) {
  int z = blockIdx.y, row = blockIdx.x, tid = threadIdx.x;
  if (z < 2) {
    const float* in = (z ? w_sw_sh : w_in_sh) + (size_t)row * DDIM;
    int rp = ((row >> 5) << 6) + (z << 5) + (row & 31);
    ushort* outr = wt12_8 + (size_t)rp * DDIM;
    float4 v = ((const float4*)in)[tid];
    ushort4v o = {f2bf(v.x), f2bf(v.y), f2bf(v.z), f2bf(v.w)};
    ((ushort4v*)outr)[tid] = o;
  } else {
    if (row >= DDIM) return;
    const float* in = w_out_sh + (size_t)row * FDIM;
    ushort* outr = wtout_8 + (size_t)row * FDIM;
#pragma unroll
    for (int i = 0; i < 2; i++) {
      float4 v = ((const float4*)in)[tid + 256 * i];
      ushort4v o = {f2bf(v.x), f2bf(v.y), f2bf(v.z), f2bf(v.w)};
      ((ushort4v*)outr)[tid + 256 * i] = o;
    }
  }
}

// ---------------- router ----------------
__global__ void k_router(const float* __restrict__ x, const float* __restrict__ rw,
                         __hip_bfloat16* __restrict__ xbf, int* __restrict__ counts,
                         int* __restrict__ top_e, float* __restrict__ top_g) {
  int t = blockIdx.x * 4 + (threadIdx.x >> 6);
  int l = threadIdx.x & 63;
  const float* xr = x + (size_t)t * DDIM;
  float acc[NEXP];
#pragma unroll
  for (int e = 0; e < NEXP; e++) acc[e] = 0.f;
#pragma unroll
  for (int i = 0; i < 16; i++) {
    int d = i * 64 + l;
    float v = xr[d];
    xbf[(size_t)t * DDIM + d] = __float2bfloat16(v);
    const float* rr = rw + (size_t)d * NEXP;
#pragma unroll
    for (int e = 0; e < NEXP; e++) acc[e] += v * rr[e];
  }
#pragma unroll
  for (int e = 0; e < NEXP; e++) {
#pragma unroll
    for (int s = 32; s > 0; s >>= 1) acc[e] += __shfl_xor(acc[e], s);
  }
  if (l == 0) {
    float b1 = -1e30f, b2 = -1e30f;
    int i1 = 0, i2 = 0;
#pragma unroll
    for (int e = 0; e < NEXP; e++) {
      float v = acc[e];
      if (v > b1) { b2 = b1; i2 = i1; b1 = v; i1 = e; }
      else if (v > b2) { b2 = v; i2 = e; }
    }
    atomicAdd(&counts[i1], 1);
    atomicAdd(&counts[i2], 1);
    top_e[t * 2 + 0] = i1; top_e[t * 2 + 1] = i2;
    top_g[t * 2 + 0] = sigmoidf_(b1); top_g[t * 2 + 1] = sigmoidf_(b2);
  }
}

__global__ void k_scan(int* __restrict__ counts, int* __restrict__ offs,
                       int* __restrict__ cursor) {
  if (threadIdx.x == 0 && blockIdx.x == 0) {
    counts[NEXP] = A_TOK;  // shared pseudo-expert
    int s = 0;
    for (int e = 0; e < NE9; e++) { offs[e] = s; s += counts[e]; cursor[e] = 0; }
  }
}

__global__ void k_dispatch(const float* __restrict__ x, const int* __restrict__ top_e,
                           const float* __restrict__ top_g, const int* __restrict__ offs,
                           int* __restrict__ cursor, int* __restrict__ slot_of,
                           __hip_bfloat16* __restrict__ y) {
  int t = blockIdx.x * 4 + (threadIdx.x >> 6);
  int l = threadIdx.x & 63;
  int e0 = top_e[t * 2 + 0], e1 = top_e[t * 2 + 1];
  float g0 = top_g[t * 2 + 0], g1 = top_g[t * 2 + 1];
  int s0 = 0, s1 = 0;
  if (l == 0) {
    s0 = offs[e0] + atomicAdd(&cursor[e0], 1);
    s1 = offs[e1] + atomicAdd(&cursor[e1], 1);
    slot_of[t * 2 + 0] = s0; slot_of[t * 2 + 1] = s1;
  }
  s0 = __shfl(s0, 0); s1 = __shfl(s1, 0);
  const float* xr = x + (size_t)t * DDIM;
#pragma unroll
  for (int i = 0; i < 16; i++) {
    int d = i * 64 + l;
    float v = xr[d];
    y[(size_t)s0 * DDIM + d] = __float2bfloat16(v * g0);
    y[(size_t)s1 * DDIM + d] = __float2bfloat16(v * g1);
  }
}

// ======== fused in+swiglu grouped GEMM (single interleaved B), 128x128, BK=32 ========
// A: bf16 [6144][1024], B: wt12 [9][4096][1024]. Wave-tile 64x64: nf0,1 = mid cols,
// nf2,3 = sw cols of the SAME output h-col -> fused SwiGLU epilogue in-lane.
// 3 rotating 16KB buffers (A 8K | B 8K) = 48KB -> 3 blocks/CU (12 waves/CU).
// Counted pipeline: stage t+2 during t; boundary s_waitcnt vmcnt(4).
__global__ __launch_bounds__(256, 3) void k_mlp1(
    const ushort* __restrict__ Abase, const ushort* __restrict__ Bbase,
    ushort* __restrict__ Obase, const int* __restrict__ d_cnt,
    const int* __restrict__ d_off) {
  constexpr int K = DDIM, NT = DDIM / 32;
  constexpr int BUF = 16384;
  __shared__ __align__(16) char smem[3 * BUF];
  int e = blockIdx.z;
  int cnt = d_cnt[e];
  int m0 = blockIdx.y * 128;
  if (m0 >= cnt) return;
  int roff = d_off[e];
  int n0 = blockIdx.x * 128;
  const ushort* B = Bbase + (size_t)e * NB1 * DDIM;
  int tid = threadIdx.x, w = tid >> 6, l = tid & 63;
  int wm = w >> 1, wn = w & 1, lr = l & 15, kg = l >> 4;
  size_t arow0 = (size_t)roff + m0;

  f32x4 acc[4][4];
#pragma unroll
  for (int i = 0; i < 4; i++)
#pragma unroll
    for (int j = 0; j < 4; j++) acc[i][j] = {0.f, 0.f, 0.f, 0.f};

  auto frag = [&](const char* base, int row) -> short8v {
    return *(const short8v*)(base + row * 64 + ((kg ^ ((row >> 1) & 3)) << 4));
  };

#pragma unroll
  for (int pt = 0; pt < 2; ++pt) {  // prologue: tiles 0,1 (4 units each)
    char* bb = smem + pt * BUF;
    int k0 = pt * 32;
    stage64(Abase, arow0, K, k0, bb, tid);
    stage64(Abase, arow0 + 64, K, k0, bb + 4096, tid);
    stage64(B, (size_t)n0, K, k0, bb + 8192, tid);
    stage64(B, (size_t)n0 + 64, K, k0, bb + 12288, tid);
  }
  VMCNT(4);
  BARRIER();

  char* b0 = smem;
  char* b1 = smem + BUF;
  char* b2 = smem + 2 * BUF;
  for (int t = 0; t < NT; ++t) {
    bool st = (t + 2) < NT;
    int k2 = (t + 2) * 32;
    short8v af[4], bf[4];
    // ---- phase 0: A-frags + B-frags nf0,1; stage A units of t+2; MFMA nf0,1 ----
#pragma unroll
    for (int mf = 0; mf < 4; mf++) af[mf] = frag(b0, wm * 64 + mf * 16 + lr);
#pragma unroll
    for (int nf = 0; nf < 2; nf++) bf[nf] = frag(b0 + 8192, wn * 64 + nf * 16 + lr);
    if (st) {
      stage64(Abase, arow0, K, k2, b2, tid);
      stage64(Abase, arow0 + 64, K, k2, b2 + 4096, tid);
    }
    BARRIER();
    __builtin_amdgcn_s_setprio(1);
#pragma unroll
    for (int nf = 0; nf < 2; nf++)
#pragma unroll
      for (int mf = 0; mf < 4; mf++)
        acc[mf][nf] = __builtin_amdgcn_mfma_f32_16x16x32_bf16(af[mf], bf[nf], acc[mf][nf], 0, 0, 0);
    __builtin_amdgcn_s_setprio(0);
    BARRIER();
    // ---- phase 1: B-frags nf2,3; stage B units of t+2; MFMA nf2,3 ----
#pragma unroll
    for (int nf = 2; nf < 4; nf++) bf[nf] = frag(b0 + 8192, wn * 64 + nf * 16 + lr);
    if (st) {
      stage64(B, (size_t)n0, K, k2, b2 + 8192, tid);
      stage64(B, (size_t)n0 + 64, K, k2, b2 + 12288, tid);
    }
    BARRIER();
    __builtin_amdgcn_s_setprio(1);
#pragma unroll
    for (int nf = 2; nf < 4; nf++)
#pragma unroll
      for (int mf = 0; mf < 4; mf++)
        acc[mf][nf] = __builtin_amdgcn_mfma_f32_16x16x32_bf16(af[mf], bf[nf], acc[mf][nf], 0, 0, 0);
    __builtin_amdgcn_s_setprio(0);
    if (t < NT - 1) {
      if (st) { VMCNT(4); } else { VMCNT(0); }
      BARRIER();
    }
    char* tmp = b0; b0 = b1; b1 = b2; b2 = tmp;
  }

  // epilogue: interleave mapping -> wave's 64 N-cols = one 64-row j-block of wt12;
  // nf0,1 = which0 (mid), nf2,3 = which1 (sw); h-col = j*32 + nf*16 + lr
  int j = (n0 >> 6) + wn;
#pragma unroll
  for (int mf = 0; mf < 4; mf++)
#pragma unroll
    for (int nf = 0; nf < 2; nf++)
#pragma unroll
      for (int r = 0; r < 4; r++) {
        int row = m0 + wm * 64 + mf * 16 + kg * 4 + r;
        if (row < cnt) {
          float mid = acc[mf][nf][r];
          float sw = acc[mf][nf + 2][r];
          float hv = mid * sigmoidf_(mid) * sw;
          int col = j * 32 + nf * 16 + lr;
          Obase[((size_t)roff + row) * FDIM + col] = f2bf(hv);
        }
      }
}

// ======== out-proj grouped GEMM, split-K=2, bf16 partials, same structure ========
// A: bf16 [6144][2048] (h), B: wt_out_t [9][1024][2048], part: bf16 [2][6144][1024]
__global__ __launch_bounds__(256, 3) void k_mlp2(
    const ushort* __restrict__ Abase, const ushort* __restrict__ Bbase,
    ushort* __restrict__ part, const int* __restrict__ d_cnt,
    const int* __restrict__ d_off) {
  constexpr int K = FDIM, NT = 1024 / 32;
  constexpr int BUF = 16384;
  __shared__ __align__(16) char smem[3 * BUF];
  int e = blockIdx.z;
  int cnt = d_cnt[e];
  int mt = blockIdx.y >> 1, kz = blockIdx.y & 1;
  int m0 = mt * 128;
  if (m0 >= cnt) return;
  int roff = d_off[e];
  int n0 = blockIdx.x * 128;
  int kbeg = kz * 1024;
  const ushort* B = Bbase + (size_t)e * DDIM * FDIM;
  int tid = threadIdx.x, w = tid >> 6, l = tid & 63;
  int wm = w >> 1, wn = w & 1, lr = l & 15, kg = l >> 4;
  size_t arow0 = (size_t)roff + m0;

  f32x4 acc[4][4];
#pragma unroll
  for (int i = 0; i < 4; i++)
#pragma unroll
    for (int j = 0; j < 4; j++) acc[i][j] = {0.f, 0.f, 0.f, 0.f};

  auto frag = [&](const char* base, int row) -> short8v {
    return *(const short8v*)(base + row * 64 + ((kg ^ ((row >> 1) & 3)) << 4));
  };

#pragma unroll
  for (int pt = 0; pt < 2; ++pt) {
    char* bb = smem + pt * BUF;
    int k0 = kbeg + pt * 32;
    stage64(Abase, arow0, K, k0, bb, tid);
    stage64(Abase, arow0 + 64, K, k0, bb + 4096, tid);
    stage64(B, (size_t)n0, K, k0, bb + 8192, tid);
    stage64(B, (size_t)n0 + 64, K, k0, bb + 12288, tid);
  }
  VMCNT(4);
  BARRIER();

  char* b0 = smem;
  char* b1 = smem + BUF;
  char* b2 = smem + 2 * BUF;
  for (int t = 0; t < NT; ++t) {
    bool st = (t + 2) < NT;
    int k2 = kbeg + (t + 2) * 32;
    short8v af[4], bf[4];
    // ---- phase 0 ----
#pragma unroll
    for (int mf = 0; mf < 4; mf++) af[mf] = frag(b0, wm * 64 + mf * 16 + lr);
#pragma unroll
    for (int nf = 0; nf < 2; nf++) bf[nf] = frag(b0 + 8192, wn * 64 + nf * 16 + lr);
    if (st) {
      stage64(Abase, arow0, K, k2, b2, tid);
      stage64(Abase, arow0 + 64, K, k2, b2 + 4096, tid);
    }
    BARRIER();
    __builtin_amdgcn_s_setprio(1);
#pragma unroll
    for (int nf = 0; nf < 2; nf++)
#pragma unroll
      for (int mf = 0; mf < 4; mf++)
        acc[mf][nf] = __builtin_amdgcn_mfma_f32_16x16x32_bf16(af[mf], bf[nf], acc[mf][nf], 0, 0, 0);
    __builtin_amdgcn_s_setprio(0);
    BARRIER();
    // ---- phase 1 ----
#pragma unroll
    for (int nf = 2; nf < 4; nf++) bf[nf] = frag(b0 + 8192, wn * 64 + nf * 16 + lr);
    if (st) {
      stage64(B, (size_t)n0, K, k2, b2 + 8192, tid);
      stage64(B, (size_t)n0 + 64, K, k2, b2 + 12288, tid);
    }
    BARRIER();
    __builtin_amdgcn_s_setprio(1);
#pragma unroll
    for (int nf = 2; nf < 4; nf++)
#pragma unroll
      for (int mf = 0; mf < 4; mf++)
        acc[mf][nf] = __builtin_amdgcn_mfma_f32_16x16x32_bf16(af[mf], bf[nf], acc[mf][nf], 0, 0, 0);
    __builtin_amdgcn_s_setprio(0);
    if (t < NT - 1) {
      if (st) { VMCNT(4); } else { VMCNT(0); }
      BARRIER();
    }
    char* tmp = b0; b0 = b1; b1 = b2; b2 = tmp;
  }

  ushort* outp = part + (size_t)kz * SLOTS_T * DDIM;
#pragma unroll
  for (int mf = 0; mf < 4; mf++)
#pragma unroll
    for (int nf = 0; nf < 4; nf++)
#pragma unroll
      for (int r = 0; r < 4; r++) {
        int row = m0 + wm * 64 + mf * 16 + kg * 4 + r;
        if (row < cnt) {
          int col = n0 + wn * 64 + nf * 16 + lr;
          outp[((size_t)roff + row) * DDIM + col] = f2bf(acc[mf][nf][r]);
        }
      }
}

// ------- combine: out[t][d] = sum over {2 kz} x {s0, s1, shared row} of bf16 partials ----
__global__ void k_combine(const ushort* __restrict__ part, const int* __restrict__ slot_of,
                          float* __restrict__ out) {
  int t = blockIdx.x, q = threadIdx.x;  // 256 threads x 4 cols
  int rows[3];
  rows[0] = slot_of[t * 2 + 0];
  rows[1] = slot_of[t * 2 + 1];
  rows[2] = SLOTS_R + t;
  size_t P = (size_t)SLOTS_T * DDIM;
  float o[4] = {0.f, 0.f, 0.f, 0.f};
#pragma unroll
  for (int kz = 0; kz < 2; kz++)
#pragma unroll
    for (int i = 0; i < 3; i++) {
      ushort4v v = *(const ushort4v*)(part + kz * P + (size_t)rows[i] * DDIM + q * 4);
#pragma unroll
      for (int j = 0; j < 4; j++) o[j] += bf2f(v[j]);
    }
  float4 ov = {o[0], o[1], o[2], o[3]};
  ((float4*)out)[(size_t)t * (DDIM / 4) + q] = ov;
}

extern "C" void kernel_launch(void* const* d_in, const int* in_sizes, int n_in,
                              void* d_out, int out_size, void* d_ws, size_t ws_size,
                              hipStream_t stream) {
  (void)in_sizes; (void)n_in; (void)out_size; (void)ws_size;
  const float* x        = (const float*)d_in[0];
  const float* router   = (const float*)d_in[1];
  const float* w_in_sh  = (const float*)d_in[2];
  const float* w_out_sh = (const float*)d_in[3];
  const float* w_sw_sh  = (const float*)d_in[4];
  const float* w_in_e   = (const float*)d_in[5];
  const float* w_sw_e   = (const float*)d_in[6];
  const float* w_out_e  = (const float*)d_in[7];
  float* out = (float*)d_out;

  char* ws = (char*)d_ws;
  size_t off = 0;
  auto alloc = [&](size_t bytes) -> char* {
    char* p = ws + off;
    off += (bytes + 255) & ~(size_t)255;
    return p;
  };
  // Ordering:
  //  - y_all ++ xbf ++ h contiguous: mlp1's 128-row A overread past row 6144 lands in h;
  //    mlp2's A overread past h lands in small bufs + guard. All count-guarded stores.
  //  - part aliases wt12 (dead after k_mlp1; k_mlp2 reads wt_out_t + h only).
  ushort* wt12     = (ushort*)alloc((size_t)NE9 * NB1 * DDIM * 2);   // 75.5 MB
  ushort* wt_out_t = (ushort*)alloc((size_t)NE9 * DDIM * FDIM * 2);  // 37.7 MB
  __hip_bfloat16* y_all = (__hip_bfloat16*)alloc((size_t)SLOTS_R * DDIM * 2);
  __hip_bfloat16* xbf   = (__hip_bfloat16*)alloc((size_t)A_TOK * DDIM * 2);
  ushort* h        = (ushort*)alloc((size_t)SLOTS_T * FDIM * 2);     // 25.2 MB
  int*   counts  = (int*)alloc(64);
  int*   offs    = (int*)alloc(64);
  int*   cursor  = (int*)alloc(64);
  int*   top_e   = (int*)alloc((size_t)A_TOK * 2 * 4);
  float* top_g   = (float*)alloc((size_t)A_TOK * 2 * 4);
  int*   slot_of = (int*)alloc((size_t)A_TOK * 2 * 4);
  (void)alloc(1 << 20);  // guard for mlp2 A-tile overread (512KB needed)
  ushort* part = wt12;   // [2][6144][1024] bf16 = 25.2 MB alias

  hipMemsetAsync(counts, 0, 64, stream);

  // weight prep
  k_tr12<<<dim3(FDIM / 64, DDIM / 64, 16), 256, 0, stream>>>(w_in_e, w_sw_e, wt12);
  k_transpose<<<dim3(DDIM / 64, FDIM / 64, NEXP), 256, 0, stream>>>(w_out_e, wt_out_t, FDIM, DDIM);
  k_cvt_sh<<<dim3(FDIM, 3), 256, 0, stream>>>(
      w_in_sh, w_sw_sh, w_out_sh,
      wt12 + (size_t)NEXP * NB1 * DDIM, wt_out_t + (size_t)NEXP * DDIM * FDIM);

  // routing
  k_router<<<dim3(A_TOK / 4), 256, 0, stream>>>(x, router, xbf, counts, top_e, top_g);
  k_scan<<<1, 64, 0, stream>>>(counts, offs, cursor);
  k_dispatch<<<dim3(A_TOK / 4), 256, 0, stream>>>(x, top_e, top_g, offs, cursor, slot_of, y_all);

  // fused in+swiglu: N = 4096 interleaved cols
  k_mlp1<<<dim3(NB1 / 128, A_TOK / 128, NE9), 256, 0, stream>>>(
      (const ushort*)y_all, wt12, h, counts, offs);

  // out-proj, split-K=2
  k_mlp2<<<dim3(DDIM / 128, (A_TOK / 128) * 2, NE9), 256, 0, stream>>>(
      h, wt_out_t, part, counts, offs);

  // combine (fully overwrites d_out -> poison-safe)
  k_combine<<<dim3(A_TOK), 256, 0, stream>>>(part, slot_of, out);
}

// Round 5
// 304.980 us; speedup vs baseline: 1.4635x; 1.0001x over previous
//
#include <hip/hip_runtime.h>
#include <hip/hip_bf16.h>

#define A_TOK 2048
#define DDIM 1024
#define FDIM 2048
#define NEXP 8
#define NE9 9                      // 8 routed + 1 shared pseudo-expert
#define SLOTS_R (2 * A_TOK)        // 4096 routed slots
#define SLOTS_T (SLOTS_R + A_TOK)  // 6144 incl. shared rows
#define NB1 (2 * FDIM)             // 4096: interleaved [w_in | w_swiglu] rows (32-col blocks)

typedef __attribute__((ext_vector_type(8))) short short8v;   // 8 bf16
typedef __attribute__((ext_vector_type(4))) float f32x4;
typedef __attribute__((ext_vector_type(4))) ushort ushort4v;

#define BARRIER() asm volatile("s_barrier" ::: "memory")
#define VMCNT(n) asm volatile("s_waitcnt vmcnt(" #n ")" ::: "memory")

__device__ __forceinline__ void lds16(const void* g, void* l) {
  __builtin_amdgcn_global_load_lds((const __attribute__((address_space(1))) void*)g,
                                   (__attribute__((address_space(3))) void*)l, 16, 0, 0);
}

__device__ __forceinline__ float sigmoidf_(float x) { return 1.f / (1.f + __expf(-x)); }
__device__ __forceinline__ ushort f2bf(float x) {
  __hip_bfloat16 b = __float2bfloat16(x);
  ushort u; __builtin_memcpy(&u, &b, 2); return u;
}
__device__ __forceinline__ float bf2f(ushort u) {
  union { unsigned int i; float f; } x; x.i = (unsigned int)u << 16; return x.f;
}

// ---------------- weight prep (vectorized: 16B/lane loads, 8B/lane stores) ----------------
// k_trA: w_in_e/w_sw_e [e][1024][2048] fp32 -> wt12[e][4096][1024] bf16, interleaved remap
// rp(f) = (f>>5)*64 + which*32 + (f&31)
__global__ void k_trA(const float* __restrict__ w_in, const float* __restrict__ w_sw,
                      ushort* __restrict__ wt12) {
  int z = blockIdx.z; int e = z & 7; int which = z >> 3;
  const float* in = (which ? w_sw : w_in) + (size_t)e * DDIM * FDIM;  // [D][F]
  ushort* outb = wt12 + (size_t)e * NB1 * DDIM;
  __shared__ ushort tile[64][68];
  int r0 = blockIdx.y * 64, c0 = blockIdx.x * 64;
  int tid = threadIdx.x;
  int rr = tid >> 4, cq = tid & 15;
#pragma unroll
  for (int i = 0; i < 4; i++) {
    int r = i * 16 + rr;
    float4 v = *(const float4*)(in + (size_t)(r0 + r) * FDIM + c0 + cq * 4);
    ushort4v o = {f2bf(v.x), f2bf(v.y), f2bf(v.z), f2bf(v.w)};
    *(ushort4v*)&tile[r][cq * 4] = o;
  }
  __syncthreads();
  int cc = tid >> 4, rq = tid & 15;
#pragma unroll
  for (int i = 0; i < 4; i++) {
    int c = i * 16 + cc;
    int f = c0 + c;
    int rp = ((f >> 5) << 6) + (which << 5) + (f & 31);
    ushort4v o = {tile[rq * 4 + 0][c], tile[rq * 4 + 1][c],
                  tile[rq * 4 + 2][c], tile[rq * 4 + 3][c]};
    *(ushort4v*)(outb + (size_t)rp * DDIM + r0 + rq * 4) = o;
  }
}

// k_trB: w_out_e [e][2048][1024] fp32 -> wt_out_t [e][1024][2048] bf16 (plain transpose)
__global__ void k_trB(const float* __restrict__ in0, ushort* __restrict__ out0) {
  const float* in = in0 + (size_t)blockIdx.z * FDIM * DDIM;   // [F][D]
  ushort* out = out0 + (size_t)blockIdx.z * DDIM * FDIM;      // [D][F]
  __shared__ ushort tile[64][68];
  int r0 = blockIdx.y * 64, c0 = blockIdx.x * 64;  // r over F, c over D
  int tid = threadIdx.x;
  int rr = tid >> 4, cq = tid & 15;
#pragma unroll
  for (int i = 0; i < 4; i++) {
    int r = i * 16 + rr;
    float4 v = *(const float4*)(in + (size_t)(r0 + r) * DDIM + c0 + cq * 4);
    ushort4v o = {f2bf(v.x), f2bf(v.y), f2bf(v.z), f2bf(v.w)};
    *(ushort4v*)&tile[r][cq * 4] = o;
  }
  __syncthreads();
  int cc = tid >> 4, rq = tid & 15;
#pragma unroll
  for (int i = 0; i < 4; i++) {
    int c = i * 16 + cc;
    ushort4v o = {tile[rq * 4 + 0][c], tile[rq * 4 + 1][c],
                  tile[rq * 4 + 2][c], tile[rq * 4 + 3][c]};
    *(ushort4v*)(out + (size_t)(c0 + c) * FDIM + r0 + rq * 4) = o;
  }
}

// shared weights: w_in_sh/w_sw_sh [F][D] -> wt12[8] rows (remap); w_out_sh [D][F] -> wt_out_t[8]
__global__ void k_cvt_sh(const float* __restrict__ w_in_sh, const float* __restrict__ w_sw_sh,
                         const float* __restrict__ w_out_sh, ushort* __restrict__ wt12_8,
                         ushort* __restrict__ wtout_8) {
  int z = blockIdx.y, row = blockIdx.x, tid = threadIdx.x;
  if (z < 2) {
    const float* in = (z ? w_sw_sh : w_in_sh) + (size_t)row * DDIM;
    int rp = ((row >> 5) << 6) + (z << 5) + (row & 31);
    ushort* outr = wt12_8 + (size_t)rp * DDIM;
    float4 v = ((const float4*)in)[tid];
    ushort4v o = {f2bf(v.x), f2bf(v.y), f2bf(v.z), f2bf(v.w)};
    ((ushort4v*)outr)[tid] = o;
  } else {
    if (row >= DDIM) return;
    const float* in = w_out_sh + (size_t)row * FDIM;
    ushort* outr = wtout_8 + (size_t)row * FDIM;
#pragma unroll
    for (int i = 0; i < 2; i++) {
      float4 v = ((const float4*)in)[tid + 256 * i];
      ushort4v o = {f2bf(v.x), f2bf(v.y), f2bf(v.z), f2bf(v.w)};
      ((ushort4v*)outr)[tid + 256 * i] = o;
    }
  }
}

// ---------------- router ----------------
__global__ void k_router(const float* __restrict__ x, const float* __restrict__ rw,
                         __hip_bfloat16* __restrict__ xbf, int* __restrict__ counts,
                         int* __restrict__ top_e, float* __restrict__ top_g) {
  int t = blockIdx.x * 4 + (threadIdx.x >> 6);
  int l = threadIdx.x & 63;
  const float* xr = x + (size_t)t * DDIM;
  float acc[NEXP];
#pragma unroll
  for (int e = 0; e < NEXP; e++) acc[e] = 0.f;
#pragma unroll
  for (int i = 0; i < 16; i++) {
    int d = i * 64 + l;
    float v = xr[d];
    xbf[(size_t)t * DDIM + d] = __float2bfloat16(v);
    const float* rr = rw + (size_t)d * NEXP;
#pragma unroll
    for (int e = 0; e < NEXP; e++) acc[e] += v * rr[e];
  }
#pragma unroll
  for (int e = 0; e < NEXP; e++) {
#pragma unroll
    for (int s = 32; s > 0; s >>= 1) acc[e] += __shfl_xor(acc[e], s);
  }
  if (l == 0) {
    float b1 = -1e30f, b2 = -1e30f;
    int i1 = 0, i2 = 0;
#pragma unroll
    for (int e = 0; e < NEXP; e++) {
      float v = acc[e];
      if (v > b1) { b2 = b1; i2 = i1; b1 = v; i1 = e; }
      else if (v > b2) { b2 = v; i2 = e; }
    }
    atomicAdd(&counts[i1], 1);
    atomicAdd(&counts[i2], 1);
    top_e[t * 2 + 0] = i1; top_e[t * 2 + 1] = i2;
    top_g[t * 2 + 0] = sigmoidf_(b1); top_g[t * 2 + 1] = sigmoidf_(b2);
  }
}

__global__ void k_scan(int* __restrict__ counts, int* __restrict__ offs,
                       int* __restrict__ cursor) {
  if (threadIdx.x == 0 && blockIdx.x == 0) {
    counts[NEXP] = A_TOK;  // shared pseudo-expert
    int s = 0;
    for (int e = 0; e < NE9; e++) { offs[e] = s; s += counts[e]; cursor[e] = 0; }
  }
}

__global__ void k_dispatch(const float* __restrict__ x, const int* __restrict__ top_e,
                           const float* __restrict__ top_g, const int* __restrict__ offs,
                           int* __restrict__ cursor, int* __restrict__ slot_of,
                           __hip_bfloat16* __restrict__ y) {
  int t = blockIdx.x * 4 + (threadIdx.x >> 6);
  int l = threadIdx.x & 63;
  int e0 = top_e[t * 2 + 0], e1 = top_e[t * 2 + 1];
  float g0 = top_g[t * 2 + 0], g1 = top_g[t * 2 + 1];
  int s0 = 0, s1 = 0;
  if (l == 0) {
    s0 = offs[e0] + atomicAdd(&cursor[e0], 1);
    s1 = offs[e1] + atomicAdd(&cursor[e1], 1);
    slot_of[t * 2 + 0] = s0; slot_of[t * 2 + 1] = s1;
  }
  s0 = __shfl(s0, 0); s1 = __shfl(s1, 0);
  const float* xr = x + (size_t)t * DDIM;
#pragma unroll
  for (int i = 0; i < 16; i++) {
    int d = i * 64 + l;
    float v = xr[d];
    y[(size_t)s0 * DDIM + d] = __float2bfloat16(v * g0);
    y[(size_t)s1 * DDIM + d] = __float2bfloat16(v * g1);
  }
}

// ======== fused in+swiglu grouped GEMM (single interleaved B), 128x128, BK=32 ========
// Structure identical to R4 (verified); addressing hoisted to pointer-increments:
// stage addr = one pointer add/K-tile, frag LDS offsets precomputed per-thread constants.
__global__ __launch_bounds__(256, 3) void k_mlp1(
    const ushort* __restrict__ Abase, const ushort* __restrict__ Bbase,
    ushort* __restrict__ Obase, const int* __restrict__ d_cnt,
    const int* __restrict__ d_off) {
  constexpr int K = DDIM, NT = DDIM / 32;
  constexpr int BUF = 16384;
  __shared__ __align__(16) char smem[3 * BUF];
  int e = blockIdx.z;
  int cnt = d_cnt[e];
  int m0 = blockIdx.y * 128;
  if (m0 >= cnt) return;
  int roff = d_off[e];
  int n0 = blockIdx.x * 128;
  const ushort* B = Bbase + (size_t)e * NB1 * DDIM;
  int tid = threadIdx.x, w = tid >> 6, l = tid & 63;
  int wm = w >> 1, wn = w & 1, lr = l & 15, kg = l >> 4;
  size_t arow0 = (size_t)roff + m0;

  // staging: thread covers (row = tid>>2, granule gg) of a 64x32 unit; swizzled source
  int srow = tid >> 2;
  int sgg = (tid & 3) ^ ((tid >> 3) & 3);
  const ushort* pA0 = Abase + (arow0 + srow) * (size_t)K + sgg * 8;
  const ushort* pA1 = pA0 + (size_t)64 * K;
  const ushort* pB0 = B + ((size_t)n0 + srow) * K + sgg * 8;
  const ushort* pB1 = pB0 + (size_t)64 * K;
  int tls = tid * 16;

  // frag LDS byte offsets (constant per thread; XOR term uniform across frags)
  int xorg = (kg ^ ((lr >> 1) & 3)) << 4;
  int offA[4], offB[4];
#pragma unroll
  for (int i = 0; i < 4; i++) {
    offA[i] = (wm * 64 + i * 16 + lr) * 64 + xorg;
    offB[i] = 8192 + (wn * 64 + i * 16 + lr) * 64 + xorg;
  }

  f32x4 acc[4][4];
#pragma unroll
  for (int i = 0; i < 4; i++)
#pragma unroll
    for (int j = 0; j < 4; j++) acc[i][j] = {0.f, 0.f, 0.f, 0.f};

#pragma unroll
  for (int pt = 0; pt < 2; ++pt) {  // prologue: tiles 0,1
    char* bb = smem + pt * BUF;
    lds16(pA0, bb + tls);         pA0 += 32;
    lds16(pA1, bb + 4096 + tls);  pA1 += 32;
    lds16(pB0, bb + 8192 + tls);  pB0 += 32;
    lds16(pB1, bb + 12288 + tls); pB1 += 32;
  }
  VMCNT(4);
  BARRIER();

  char* b0 = smem;
  char* b1 = smem + BUF;
  char* b2 = smem + 2 * BUF;
  for (int t = 0; t < NT; ++t) {
    bool st = (t + 2) < NT;
    short8v af[4], bf[4];
    // ---- phase 0: A-frags + B-frags nf0,1; stage A units of t+2; MFMA nf0,1 ----
#pragma unroll
    for (int mf = 0; mf < 4; mf++) af[mf] = *(const short8v*)(b0 + offA[mf]);
#pragma unroll
    for (int nf = 0; nf < 2; nf++) bf[nf] = *(const short8v*)(b0 + offB[nf]);
    if (st) {
      lds16(pA0, b2 + tls);
      lds16(pA1, b2 + 4096 + tls);
    }
    pA0 += 32; pA1 += 32;
    BARRIER();
    __builtin_amdgcn_s_setprio(1);
#pragma unroll
    for (int nf = 0; nf < 2; nf++)
#pragma unroll
      for (int mf = 0; mf < 4; mf++)
        acc[mf][nf] = __builtin_amdgcn_mfma_f32_16x16x32_bf16(af[mf], bf[nf], acc[mf][nf], 0, 0, 0);
    __builtin_amdgcn_s_setprio(0);
    BARRIER();
    // ---- phase 1: B-frags nf2,3; stage B units of t+2; MFMA nf2,3 ----
#pragma unroll
    for (int nf = 2; nf < 4; nf++) bf[nf] = *(const short8v*)(b0 + offB[nf]);
    if (st) {
      lds16(pB0, b2 + 8192 + tls);
      lds16(pB1, b2 + 12288 + tls);
    }
    pB0 += 32; pB1 += 32;
    BARRIER();
    __builtin_amdgcn_s_setprio(1);
#pragma unroll
    for (int nf = 2; nf < 4; nf++)
#pragma unroll
      for (int mf = 0; mf < 4; mf++)
        acc[mf][nf] = __builtin_amdgcn_mfma_f32_16x16x32_bf16(af[mf], bf[nf], acc[mf][nf], 0, 0, 0);
    __builtin_amdgcn_s_setprio(0);
    if (t < NT - 1) {
      if (st) { VMCNT(4); } else { VMCNT(0); }
      BARRIER();
    }
    char* tmp = b0; b0 = b1; b1 = b2; b2 = tmp;
  }

  // epilogue: nf0,1 = mid, nf2,3 = sw of the SAME h-col (interleaved B rows)
  int j = (n0 >> 6) + wn;
#pragma unroll
  for (int mf = 0; mf < 4; mf++)
#pragma unroll
    for (int nf = 0; nf < 2; nf++)
#pragma unroll
      for (int r = 0; r < 4; r++) {
        int row = m0 + wm * 64 + mf * 16 + kg * 4 + r;
        if (row < cnt) {
          float mid = acc[mf][nf][r];
          float sw = acc[mf][nf + 2][r];
          float hv = mid * sigmoidf_(mid) * sw;
          int col = j * 32 + nf * 16 + lr;
          Obase[((size_t)roff + row) * FDIM + col] = f2bf(hv);
        }
      }
}

// ======== out-proj grouped GEMM, split-K=2, bf16 partials, same structure ========
__global__ __launch_bounds__(256, 3) void k_mlp2(
    const ushort* __restrict__ Abase, const ushort* __restrict__ Bbase,
    ushort* __restrict__ part, const int* __restrict__ d_cnt,
    const int* __restrict__ d_off) {
  constexpr int K = FDIM, NT = 1024 / 32;
  constexpr int BUF = 16384;
  __shared__ __align__(16) char smem[3 * BUF];
  int e = blockIdx.z;
  int cnt = d_cnt[e];
  int mt = blockIdx.y >> 1, kz = blockIdx.y & 1;
  int m0 = mt * 128;
  if (m0 >= cnt) return;
  int roff = d_off[e];
  int n0 = blockIdx.x * 128;
  int kbeg = kz * 1024;
  const ushort* B = Bbase + (size_t)e * DDIM * FDIM;
  int tid = threadIdx.x, w = tid >> 6, l = tid & 63;
  int wm = w >> 1, wn = w & 1, lr = l & 15, kg = l >> 4;
  size_t arow0 = (size_t)roff + m0;

  int srow = tid >> 2;
  int sgg = (tid & 3) ^ ((tid >> 3) & 3);
  const ushort* pA0 = Abase + (arow0 + srow) * (size_t)K + kbeg + sgg * 8;
  const ushort* pA1 = pA0 + (size_t)64 * K;
  const ushort* pB0 = B + ((size_t)n0 + srow) * K + kbeg + sgg * 8;
  const ushort* pB1 = pB0 + (size_t)64 * K;
  int tls = tid * 16;

  int xorg = (kg ^ ((lr >> 1) & 3)) << 4;
  int offA[4], offB[4];
#pragma unroll
  for (int i = 0; i < 4; i++) {
    offA[i] = (wm * 64 + i * 16 + lr) * 64 + xorg;
    offB[i] = 8192 + (wn * 64 + i * 16 + lr) * 64 + xorg;
  }

  f32x4 acc[4][4];
#pragma unroll
  for (int i = 0; i < 4; i++)
#pragma unroll
    for (int j = 0; j < 4; j++) acc[i][j] = {0.f, 0.f, 0.f, 0.f};

#pragma unroll
  for (int pt = 0; pt < 2; ++pt) {
    char* bb = smem + pt * BUF;
    lds16(pA0, bb + tls);         pA0 += 32;
    lds16(pA1, bb + 4096 + tls);  pA1 += 32;
    lds16(pB0, bb + 8192 + tls);  pB0 += 32;
    lds16(pB1, bb + 12288 + tls); pB1 += 32;
  }
  VMCNT(4);
  BARRIER();

  char* b0 = smem;
  char* b1 = smem + BUF;
  char* b2 = smem + 2 * BUF;
  for (int t = 0; t < NT; ++t) {
    bool st = (t + 2) < NT;
    short8v af[4], bf[4];
#pragma unroll
    for (int mf = 0; mf < 4; mf++) af[mf] = *(const short8v*)(b0 + offA[mf]);
#pragma unroll
    for (int nf = 0; nf < 2; nf++) bf[nf] = *(const short8v*)(b0 + offB[nf]);
    if (st) {
      lds16(pA0, b2 + tls);
      lds16(pA1, b2 + 4096 + tls);
    }
    pA0 += 32; pA1 += 32;
    BARRIER();
    __builtin_amdgcn_s_setprio(1);
#pragma unroll
    for (int nf = 0; nf < 2; nf++)
#pragma unroll
      for (int mf = 0; mf < 4; mf++)
        acc[mf][nf] = __builtin_amdgcn_mfma_f32_16x16x32_bf16(af[mf], bf[nf], acc[mf][nf], 0, 0, 0);
    __builtin_amdgcn_s_setprio(0);
    BARRIER();
#pragma unroll
    for (int nf = 2; nf < 4; nf++) bf[nf] = *(const short8v*)(b0 + offB[nf]);
    if (st) {
      lds16(pB0, b2 + 8192 + tls);
      lds16(pB1, b2 + 12288 + tls);
    }
    pB0 += 32; pB1 += 32;
    BARRIER();
    __builtin_amdgcn_s_setprio(1);
#pragma unroll
    for (int nf = 2; nf < 4; nf++)
#pragma unroll
      for (int mf = 0; mf < 4; mf++)
        acc[mf][nf] = __builtin_amdgcn_mfma_f32_16x16x32_bf16(af[mf], bf[nf], acc[mf][nf], 0, 0, 0);
    __builtin_amdgcn_s_setprio(0);
    if (t < NT - 1) {
      if (st) { VMCNT(4); } else { VMCNT(0); }
      BARRIER();
    }
    char* tmp = b0; b0 = b1; b1 = b2; b2 = tmp;
  }

  ushort* outp = part + (size_t)kz * SLOTS_T * DDIM;
#pragma unroll
  for (int mf = 0; mf < 4; mf++)
#pragma unroll
    for (int nf = 0; nf < 4; nf++)
#pragma unroll
      for (int r = 0; r < 4; r++) {
        int row = m0 + wm * 64 + mf * 16 + kg * 4 + r;
        if (row < cnt) {
          int col = n0 + wn * 64 + nf * 16 + lr;
          outp[((size_t)roff + row) * DDIM + col] = f2bf(acc[mf][nf][r]);
        }
      }
}

// ------- combine: out[t][d] = sum over {2 kz} x {s0, s1, shared row} of bf16 partials ----
__global__ void k_combine(const ushort* __restrict__ part, const int* __restrict__ slot_of,
                          float* __restrict__ out) {
  int t = blockIdx.x, q = threadIdx.x;
  int rows[3];
  rows[0] = slot_of[t * 2 + 0];
  rows[1] = slot_of[t * 2 + 1];
  rows[2] = SLOTS_R + t;
  size_t P = (size_t)SLOTS_T * DDIM;
  float o[4] = {0.f, 0.f, 0.f, 0.f};
#pragma unroll
  for (int kz = 0; kz < 2; kz++)
#pragma unroll
    for (int i = 0; i < 3; i++) {
      ushort4v v = *(const ushort4v*)(part + kz * P + (size_t)rows[i] * DDIM + q * 4);
#pragma unroll
      for (int j = 0; j < 4; j++) o[j] += bf2f(v[j]);
    }
  float4 ov = {o[0], o[1], o[2], o[3]};
  ((float4*)out)[(size_t)t * (DDIM / 4) + q] = ov;
}

extern "C" void kernel_launch(void* const* d_in, const int* in_sizes, int n_in,
                              void* d_out, int out_size, void* d_ws, size_t ws_size,
                              hipStream_t stream) {
  (void)in_sizes; (void)n_in; (void)out_size; (void)ws_size;
  const float* x        = (const float*)d_in[0];
  const float* router   = (const float*)d_in[1];
  const float* w_in_sh  = (const float*)d_in[2];
  const float* w_out_sh = (const float*)d_in[3];
  const float* w_sw_sh  = (const float*)d_in[4];
  const float* w_in_e   = (const float*)d_in[5];
  const float* w_sw_e   = (const float*)d_in[6];
  const float* w_out_e  = (const float*)d_in[7];
  float* out = (float*)d_out;

  char* ws = (char*)d_ws;
  size_t off = 0;
  auto alloc = [&](size_t bytes) -> char* {
    char* p = ws + off;
    off += (bytes + 255) & ~(size_t)255;
    return p;
  };
  // Ordering: y_all ++ xbf ++ h contiguous (A-matrix of 6144 rows; overreads in-bounds).
  // part aliases wt12 (dead after k_mlp1; k_mlp2 reads wt_out_t + h only).
  ushort* wt12     = (ushort*)alloc((size_t)NE9 * NB1 * DDIM * 2);   // 75.5 MB
  ushort* wt_out_t = (ushort*)alloc((size_t)NE9 * DDIM * FDIM * 2);  // 37.7 MB
  __hip_bfloat16* y_all = (__hip_bfloat16*)alloc((size_t)SLOTS_R * DDIM * 2);
  __hip_bfloat16* xbf   = (__hip_bfloat16*)alloc((size_t)A_TOK * DDIM * 2);
  ushort* h        = (ushort*)alloc((size_t)SLOTS_T * FDIM * 2);     // 25.2 MB
  int*   counts  = (int*)alloc(64);
  int*   offs    = (int*)alloc(64);
  int*   cursor  = (int*)alloc(64);
  int*   top_e   = (int*)alloc((size_t)A_TOK * 2 * 4);
  float* top_g   = (float*)alloc((size_t)A_TOK * 2 * 4);
  int*   slot_of = (int*)alloc((size_t)A_TOK * 2 * 4);
  (void)alloc(1 << 20);  // guard
  ushort* part = wt12;   // [2][6144][1024] bf16 = 25.2 MB alias

  hipMemsetAsync(counts, 0, 64, stream);

  // weight prep (vectorized)
  k_trA<<<dim3(FDIM / 64, DDIM / 64, 16), 256, 0, stream>>>(w_in_e, w_sw_e, wt12);
  k_trB<<<dim3(DDIM / 64, FDIM / 64, NEXP), 256, 0, stream>>>(w_out_e, wt_out_t);
  k_cvt_sh<<<dim3(FDIM, 3), 256, 0, stream>>>(
      w_in_sh, w_sw_sh, w_out_sh,
      wt12 + (size_t)NEXP * NB1 * DDIM, wt_out_t + (size_t)NEXP * DDIM * FDIM);

  // routing
  k_router<<<dim3(A_TOK / 4), 256, 0, stream>>>(x, router, xbf, counts, top_e, top_g);
  k_scan<<<1, 64, 0, stream>>>(counts, offs, cursor);
  k_dispatch<<<dim3(A_TOK / 4), 256, 0, stream>>>(x, top_e, top_g, offs, cursor, slot_of, y_all);

  // fused in+swiglu: N = 4096 interleaved cols
  k_mlp1<<<dim3(NB1 / 128, A_TOK / 128, NE9), 256, 0, stream>>>(
      (const ushort*)y_all, wt12, h, counts, offs);

  // out-proj, split-K=2
  k_mlp2<<<dim3(DDIM / 128, (A_TOK / 128) * 2, NE9), 256, 0, stream>>>(
      h, wt_out_t, part, counts, offs);

  // combine (fully overwrites d_out -> poison-safe)
  k_combine<<<dim3(A_TOK), 256, 0, stream>>>(part, slot_of, out);
}